// Round 19
// baseline (670.904 us; speedup 1.0000x reference)
//
#include <hip/hip_runtime.h>
#include <hip/hip_bf16.h>
#include <stdint.h>

using f32x4  = __attribute__((ext_vector_type(4))) float;
using bf16x8 = __attribute__((ext_vector_type(8))) short;
using bf16x4 = __attribute__((ext_vector_type(4))) short;

#define NB   4
#define NC   128
#define NT   8192
#define TL   64
#define NLAYER 20
#define GROWB 272
#define CONVN (NLAYER * 256 * 256)
#define WOUTN (NLAYER * 128 * 128)
#define PACKB ((CONVN + WOUTN + 255) / 256)
#define TRANB ((NT / 64) * (NC / 64) * NB)
#define FLAGN (NLAYER * NB * 128)

__device__ __forceinline__ short f2b(float f) {
  union { float f; unsigned u; } v; v.f = f;
  unsigned r = v.u + 0x7FFFu + ((v.u >> 16) & 1u);   // RNE
  return (short)(r >> 16);
}

__device__ __forceinline__ float b2f(short s) {
  union { unsigned u; float f; } v;
  v.u = ((unsigned)(unsigned short)s) << 16;
  return v.f;
}

__device__ __forceinline__ f32x4 mfma16(bf16x8 a, bf16x8 b, f32x4 c) {
  return __builtin_amdgcn_mfma_f32_16x16x32_bf16(a, b, c, 0, 0, 0);
}

__device__ __forceinline__ void gl_lds16(const void* g, void* l) {
  __builtin_amdgcn_global_load_lds(
      (const __attribute__((address_space(1))) void*)g,
      (__attribute__((address_space(3))) void*)l, 16, 0, 0);
}

// Fused prep: pack weights + transpose x -> bf16 swizzled rows.
__global__ void prep(const float* __restrict__ x,
                     const float* __restrict__ w_conv,
                     const float* __restrict__ w_out,
                     short* __restrict__ xtb,
                     short* __restrict__ wcb, short* __restrict__ wob) {
  __shared__ float tile[64][65];
  if (blockIdx.x < PACKB) {
    const int idx = blockIdx.x * 256 + threadIdx.x;
    if (idx < CONVN) {
      const int k = idx & 255, o = (idx >> 8) & 255, lyr = idx >> 16;
      const int tap = k >> 7, c = k & 127;
      wcb[idx] = f2b(w_conv[(((size_t)lyr * 256 + o) * 128 + c) * 2 + tap]);
    } else if (idx < CONVN + WOUTN) {
      const int j = idx - CONVN;
      wob[j] = f2b(w_out[j]);
    }
    return;
  }
  const int bid2 = blockIdx.x - PACKB;
  const int t0 = (bid2 & 127) * 64;
  const int c0 = ((bid2 >> 7) & 1) * 64;
  const int b  = bid2 >> 8;
  const int lane = threadIdx.x & 63;
  const int r4   = threadIdx.x >> 6;
  #pragma unroll
  for (int i = 0; i < 16; ++i) {
    const int cl = i * 4 + r4;
    tile[cl][lane] = x[((size_t)(b * NC + c0 + cl)) * NT + t0 + lane];
  }
  __syncthreads();
  #pragma unroll
  for (int it = 0; it < 2; ++it) {
    const int idx = it * 256 + threadIdx.x;
    const int r  = idx >> 3;
    const int gi = idx & 7;
    bf16x8 v;
    #pragma unroll
    for (int jj = 0; jj < 8; ++jj) v[jj] = f2b(tile[gi * 8 + jj][r]);
    const int t = t0 + r;
    const int ci = ((c0 >> 3) + gi) ^ (t & 7);
    *(bf16x8*)((char*)xtb + ((size_t)(b * NT + t)) * 256 + ci * 16) = v;
  }
}

// Persistent dataflow kernel (requires cooperative co-residency).
__global__ __launch_bounds__(512, 4)
void wavenet_persist(const short* __restrict__ wcb,
                     const float* __restrict__ b_conv,
                     const short* __restrict__ wob,
                     const float* __restrict__ b_out,
                     short* __restrict__ xb0,
                     short* __restrict__ xb1,
                     float* __restrict__ out,
                     int* __restrict__ flags,
                     int* __restrict__ acks)
{
  __shared__ char ldsXC[TL * 256];
  __shared__ char ldsXP[TL * 256];
  __shared__ char ldsG[TL * GROWB];

  const int tid = threadIdx.x;
  const int w   = tid >> 6;
  const int l   = tid & 63;
  const int lh  = l & 15;
  const int lq  = l >> 4;
  const int o0  = 16 * w + lq * 4;
  const int uid = (blockIdx.x & 7) * 64 + (blockIdx.x >> 3);
  const int b   = uid >> 7;
  const int j   = uid & 127;
  const int t0  = j * 64;
  const f32x4 fz = {0.f, 0.f, 0.f, 0.f};
  const size_t XOFFS = (size_t)NB * NC * NT;

  {
    const char* xcg = (const char*)xb0 + ((size_t)(b * NT + t0)) * 256;
    const int off = w * 2048 + l * 16;
    gl_lds16(xcg + off, ldsXC + off);
    gl_lds16(xcg + off + 1024, ldsXC + off + 1024);
  }

  int dprev = 0;
  for (int i = 0; i < NLAYER; ++i) {
    const int d = 1 << (i < 10 ? i : i - 10);
    const short* xbin  = (i & 1) ? xb1 : xb0;
    short*       xbout = (i & 1) ? xb0 : xb1;

    if (i > 0) {
      int jx = -1;
      if (d < 64) { if (j > 0) jx = j - 1; }
      else        { if (j >= (d >> 6)) jx = j - (d >> 6); }
      if (tid == 0 && jx >= 0) {
        int* fp = &flags[((i - 1) * NB + b) * 128 + jx];
        while (__hip_atomic_fetch_add(fp, 0, __ATOMIC_RELAXED,
                                      __HIP_MEMORY_SCOPE_AGENT) == 0)
          __builtin_amdgcn_s_sleep(8);
        __builtin_amdgcn_fence(__ATOMIC_ACQUIRE, "agent");
      }
      __syncthreads();
    }

    if (t0 >= d) {
      const char* xpg = (const char*)xbin + ((size_t)(b * NT + t0 - d)) * 256;
      const int off = w * 2048 + l * 16;
      gl_lds16(xpg + off, ldsXP + off);
      gl_lds16(xpg + off + 1024, ldsXP + off + 1024);
    } else {
      const int row = tid >> 3, j8 = tid & 7;
      const int tp = t0 + row - d;
      char* dst = ldsXP + row * 256;
      if (tp >= 0) {
        const char* src = (const char*)xbin + ((size_t)(b * NT + tp)) * 256;
        *(bf16x8*)(dst + j8 * 16)       = *(const bf16x8*)(src + j8 * 16);
        *(bf16x8*)(dst + j8 * 16 + 128) = *(const bf16x8*)(src + j8 * 16 + 128);
      } else {
        bf16x8 z = {0, 0, 0, 0, 0, 0, 0, 0};
        *(bf16x8*)(dst + j8 * 16)       = z;
        *(bf16x8*)(dst + j8 * 16 + 128) = z;
      }
    }
    __syncthreads();                                   // staging done
    if (tid == 0)
      __hip_atomic_store(&acks[(i * NB + b) * 128 + j], 1,
                         __ATOMIC_RELAXED, __HIP_MEMORY_SCOPE_AGENT);

    f32x4 acc1[2][4];
    #pragma unroll
    for (int mi = 0; mi < 2; ++mi)
      #pragma unroll
      for (int n = 0; n < 4; ++n) acc1[mi][n] = fz;
    const short* wl = wcb + (size_t)i * 65536;
    #pragma unroll
    for (int ks = 0; ks < 8; ++ks) {
      const bf16x8 a0 = *(const bf16x8*)(wl + (16 * w + lh) * 256 + ks * 32 + lq * 8);
      const bf16x8 a1 = *(const bf16x8*)(wl + (128 + 16 * w + lh) * 256 + ks * 32 + lq * 8);
      const char* base = (ks < 4) ? ldsXP : ldsXC;
      const int dd = (ks < 4) ? d : 0;
      #pragma unroll
      for (int n = 0; n < 4; ++n) {
        const int tt = n * 16 + lh;
        const int ci = ((ks & 3) * 4 + lq) ^ ((tt - dd) & 7);
        const bf16x8 bb = *(const bf16x8*)(base + tt * 256 + ci * 16);
        acc1[0][n] = mfma16(a0, bb, acc1[0][n]);
        acc1[1][n] = mfma16(a1, bb, acc1[1][n]);
      }
    }

    {
      float ba[4], bs[4];
      #pragma unroll
      for (int r = 0; r < 4; ++r) {
        ba[r] = b_conv[i * 256 + o0 + r];
        bs[r] = b_conv[i * 256 + 128 + o0 + r];
      }
      #pragma unroll
      for (int n = 0; n < 4; ++n) {
        bf16x4 g4;
        #pragma unroll
        for (int r = 0; r < 4; ++r) {
          const float za = acc1[0][n][r] + ba[r];
          const float zb = acc1[1][n][r] + bs[r];
          const float th = 1.f - 2.f / (1.f + __expf(2.f * za));
          const float sg = 1.f / (1.f + __expf(-zb));
          g4[r] = f2b(th * sg);
        }
        const int tt = n * 16 + lh;
        *(bf16x4*)(ldsG + tt * GROWB + o0 * 2) = g4;
      }
    }
    __syncthreads();

    f32x4 acc2[4];
    #pragma unroll
    for (int n = 0; n < 4; ++n) acc2[n] = fz;
    const short* wol = wob + (size_t)i * 16384;
    #pragma unroll
    for (int ks = 0; ks < 4; ++ks) {
      const bf16x8 a = *(const bf16x8*)(wol + (16 * w + lh) * 128 + ks * 32 + lq * 8);
      #pragma unroll
      for (int n = 0; n < 4; ++n) {
        const int tt = n * 16 + lh;
        const bf16x8 bb = *(const bf16x8*)(ldsG + tt * GROWB + ks * 64 + lq * 16);
        acc2[n] = mfma16(a, bb, acc2[n]);
      }
    }

    f32x4 xn4[4];
    {
      float bo[4];
      #pragma unroll
      for (int r = 0; r < 4; ++r) bo[r] = b_out[i * 128 + o0 + r];
      float* skipBase = out + XOFFS + ((size_t)((i * NB + b) * NC)) * NT + t0;
      #pragma unroll
      for (int n = 0; n < 4; ++n) {
        const int tt = n * 16 + lh;
        const int ci = (o0 >> 3) ^ (tt & 7);
        const bf16x4 h4 = *(const bf16x4*)(ldsXC + tt * 256 + ci * 16 + (o0 & 7) * 2);
        f32x4 s4, xn;
        #pragma unroll
        for (int r = 0; r < 4; ++r) {
          s4[r] = acc2[n][r] + bo[r];
          xn[r] = s4[r] + b2f(h4[r]);
          __builtin_nontemporal_store(s4[r], skipBase + (size_t)(o0 + r) * NT + tt);
        }
        if (i < NLAYER - 1) {
          bf16x4 x4;
          #pragma unroll
          for (int r = 0; r < 4; ++r) x4[r] = f2b(xn[r]);
          *(bf16x4*)(ldsXC + tt * 256 + ci * 16 + (o0 & 7) * 2) = x4;
        } else {
          xn4[n] = xn;
        }
      }
    }
    __syncthreads();

    if (i < NLAYER - 1) {
      if (i >= 1) {
        const int de = (dprev < 64) ? 1 : (dprev >> 6);
        const int jr = j + de;
        if (tid == 0 && jr < 128) {
          int* ap = &acks[((i - 1) * NB + b) * 128 + jr];
          while (__hip_atomic_fetch_add(ap, 0, __ATOMIC_RELAXED,
                                        __HIP_MEMORY_SCOPE_AGENT) == 0)
            __builtin_amdgcn_s_sleep(8);
        }
        __syncthreads();
      }
      char* dstBase = (char*)xbout + ((size_t)(b * NT + t0)) * 256;
      #pragma unroll
      for (int k = 0; k < 2; ++k) {
        const int idx = k * 512 + tid;
        const int r = idx >> 4, p = idx & 15;
        *(f32x4*)(dstBase + r * 256 + p * 16) = *(const f32x4*)(ldsXC + r * 256 + p * 16);
      }
      __syncthreads();
      if (tid == 0)
        __hip_atomic_store(&flags[(i * NB + b) * 128 + j], 1,
                           __ATOMIC_RELEASE, __HIP_MEMORY_SCOPE_AGENT);
    } else {
      #pragma unroll
      for (int n = 0; n < 4; ++n) {
        const int tt = n * 16 + lh;
        #pragma unroll
        for (int r = 0; r < 4; ++r)
          *(short*)(ldsXC + (o0 + r) * 128 + tt * 2) = f2b(xn4[n][r]);
      }
      __syncthreads();
      float* xBase = out + ((size_t)(b * NC)) * NT + t0;
      const int j16 = tid & 15;
      #pragma unroll
      for (int k = 0; k < 4; ++k) {
        const int o = k * 32 + (tid >> 4);
        const bf16x4 v = *(const bf16x4*)(ldsXC + o * 128 + j16 * 8);
        f32x4 f;
        #pragma unroll
        for (int r = 0; r < 4; ++r) f[r] = b2f(v[r]);
        __builtin_nontemporal_store(f, (f32x4*)(xBase + (size_t)o * NT + j16 * 4));
      }
    }
    dprev = d;
  }
}

// ---- R17 fallback kernels ----
__global__ __launch_bounds__(512, 4)
void wavenet_pair(const short* __restrict__ wcb,
                  const float* __restrict__ b_conv,
                  const short* __restrict__ wob,
                  const float* __restrict__ b_out,
                  const short* __restrict__ xbin,
                  short* __restrict__ xbout,
                  float* __restrict__ out,
                  int L, int d1, int d2)
{
  __shared__ char ldsY[80 * 256];
  __shared__ char ldsXG[88 * 256 + 80 * 256];
  char* X = ldsXG;
  char* G = ldsXG + 88 * 256;
  char* S = ldsXG;

  const int tid = threadIdx.x;
  const int w = tid >> 6, l = tid & 63, lh = l & 15, lq = l >> 4;
  const int o0 = 16 * w + lq * 4;
  const int uid = (blockIdx.x & 7) * 64 + (blockIdx.x >> 3);
  const int b   = uid >> 7;
  const int t0  = (uid & 127) * 64;
  const bool zhalo = (t0 == 0);
  const f32x4 fz = {0.f, 0.f, 0.f, 0.f};
  const size_t XOFFS = (size_t)NB * NC * NT;

  if (!zhalo) {
    const char* src = (const char*)xbin + ((size_t)(b * NT + t0 - 24)) * 256;
    #pragma unroll
    for (int k = 0; k < 3; ++k) {
      const int off = k * 8192 + tid * 16;
      if (off < 88 * 256) gl_lds16(src + off, X + off);
    }
  } else {
    if (tid * 16 < 6144) {
      bf16x8 z = {0, 0, 0, 0, 0, 0, 0, 0};
      *(bf16x8*)(X + tid * 16) = z;
    }
    const char* src = (const char*)xbin + ((size_t)(b * NT)) * 256;
    gl_lds16(src + tid * 16,        X + 6144 + tid * 16);
    gl_lds16(src + tid * 16 + 8192, X + 6144 + tid * 16 + 8192);
  }
  __syncthreads();

  f32x4 acc1[2][5];
  #pragma unroll
  for (int mi = 0; mi < 2; ++mi)
    #pragma unroll
    for (int nn = 0; nn < 5; ++nn) acc1[mi][nn] = fz;
  {
    const short* wl = wcb + (size_t)L * 65536;
    #pragma unroll
    for (int ks = 0; ks < 8; ++ks) {
      const bf16x8 a0 = *(const bf16x8*)(wl + (16 * w + lh) * 256 + ks * 32 + lq * 8);
      const bf16x8 a1 = *(const bf16x8*)(wl + (128 + 16 * w + lh) * 256 + ks * 32 + lq * 8);
      const int dd = (ks < 4) ? d1 : 0;
      #pragma unroll
      for (int nn = 0; nn < 5; ++nn) {
        const int p = 8 + nn * 16 + lh - dd;
        const int ci = ((ks & 3) * 4 + lq) ^ (p & 7);
        const bf16x8 bb = *(const bf16x8*)(X + p * 256 + ci * 16);
        acc1[0][nn] = mfma16(a0, bb, acc1[0][nn]);
        acc1[1][nn] = mfma16(a1, bb, acc1[1][nn]);
      }
    }
  }
  {
    float ba[4], bs[4];
    #pragma unroll
    for (int r = 0; r < 4; ++r) {
      ba[r] = b_conv[L * 256 + o0 + r];
      bs[r] = b_conv[L * 256 + 128 + o0 + r];
    }
    #pragma unroll
    for (int nn = 0; nn < 5; ++nn) {
      bf16x4 g4;
      #pragma unroll
      for (int r = 0; r < 4; ++r) {
        const float za = acc1[0][nn][r] + ba[r];
        const float zb = acc1[1][nn][r] + bs[r];
        const float th = 1.f - 2.f / (1.f + __expf(2.f * za));
        const float sg = 1.f / (1.f + __expf(-zb));
        g4[r] = f2b(th * sg);
      }
      const int q = nn * 16 + lh;
      const int ci = (o0 >> 3) ^ (q & 7);
      *(bf16x4*)(G + q * 256 + ci * 16 + (o0 & 7) * 2) = g4;
    }
  }
  __syncthreads();

  f32x4 s4vL[4];
  {
    f32x4 acc2[5];
    #pragma unroll
    for (int nn = 0; nn < 5; ++nn) acc2[nn] = fz;
    const short* wol = wob + (size_t)L * 16384;
    #pragma unroll
    for (int ks = 0; ks < 4; ++ks) {
      const bf16x8 a = *(const bf16x8*)(wol + (16 * w + lh) * 128 + ks * 32 + lq * 8);
      #pragma unroll
      for (int nn = 0; nn < 5; ++nn) {
        const int q = nn * 16 + lh;
        const int ci = (ks * 4 + lq) ^ (q & 7);
        const bf16x8 bb = *(const bf16x8*)(G + q * 256 + ci * 16);
        acc2[nn] = mfma16(a, bb, acc2[nn]);
      }
    }
    float bo[4];
    #pragma unroll
    for (int r = 0; r < 4; ++r) bo[r] = b_out[L * 128 + o0 + r];
    #pragma unroll
    for (int nn = 0; nn < 5; ++nn) {
      const int q = nn * 16 + lh;
      const int p = q + 8;
      const int ci = (o0 >> 3) ^ (q & 7);
      const bf16x4 h4 = *(const bf16x4*)(X + p * 256 + ci * 16 + (o0 & 7) * 2);
      f32x4 s4, xn;
      #pragma unroll
      for (int r = 0; r < 4; ++r) {
        s4[r] = acc2[nn][r] + bo[r];
        xn[r] = s4[r] + b2f(h4[r]);
      }
      if (nn >= 1) s4vL[nn - 1] = s4;
      bf16x4 x4;
      #pragma unroll
      for (int r = 0; r < 4; ++r) x4[r] = f2b(xn[r]);
      if (zhalo && nn == 0) { x4[0] = 0; x4[1] = 0; x4[2] = 0; x4[3] = 0; }
      *(bf16x4*)(ldsY + q * 256 + ci * 16 + (o0 & 7) * 2) = x4;
    }
  }
  __syncthreads();

  #pragma unroll
  for (int nn = 0; nn < 4; ++nn) {
    const int tt = nn * 16 + lh;
    #pragma unroll
    for (int r = 0; r < 4; ++r) {
      const int o  = o0 + r;
      const int lg = tt >> 2;
      const int pg = (lg & 8) | ((lg ^ (o & 7)) & 7);
      *(float*)(S + o * 256 + pg * 16 + (tt & 3) * 4) = s4vL[nn][r];
    }
  }
  __syncthreads();

  f32x4 acc1b[2][4];
  #pragma unroll
  for (int mi = 0; mi < 2; ++mi)
    #pragma unroll
    for (int n = 0; n < 4; ++n) acc1b[mi][n] = fz;
  {
    float* skipBase = out + XOFFS + ((size_t)((L * NB + b) * NC)) * NT + t0;
    const int j8 = tid & 7;
    #pragma unroll
    for (int half = 0; half < 2; ++half) {
      const int o = half * 64 + (tid >> 3);
      #pragma unroll
      for (int k = 0; k < 2; ++k) {
        const int pg = (k * 8) | ((j8 ^ (o & 7)) & 7);
        const f32x4 v = *(const f32x4*)(S + o * 256 + pg * 16);
        __builtin_nontemporal_store(v, (f32x4*)(skipBase + (size_t)o * NT + j8 * 4 + k * 32));
      }
    }
    const short* wl2 = wcb + (size_t)(L + 1) * 65536;
    #pragma unroll
    for (int ks = 0; ks < 8; ++ks) {
      const bf16x8 a0 = *(const bf16x8*)(wl2 + (16 * w + lh) * 256 + ks * 32 + lq * 8);
      const bf16x8 a1 = *(const bf16x8*)(wl2 + (128 + 16 * w + lh) * 256 + ks * 32 + lq * 8);
      const int dd = (ks < 4) ? d2 : 0;
      #pragma unroll
      for (int n = 0; n < 4; ++n) {
        const int qy = 16 + n * 16 + lh - dd;
        const int ci = ((ks & 3) * 4 + lq) ^ (qy & 7);
        const bf16x8 bb = *(const bf16x8*)(ldsY + qy * 256 + ci * 16);
        acc1b[0][n] = mfma16(a0, bb, acc1b[0][n]);
        acc1b[1][n] = mfma16(a1, bb, acc1b[1][n]);
      }
    }
  }
  __syncthreads();

  {
    float ba[4], bs[4];
    #pragma unroll
    for (int r = 0; r < 4; ++r) {
      ba[r] = b_conv[(L + 1) * 256 + o0 + r];
      bs[r] = b_conv[(L + 1) * 256 + 128 + o0 + r];
    }
    #pragma unroll
    for (int n = 0; n < 4; ++n) {
      bf16x4 g4;
      #pragma unroll
      for (int r = 0; r < 4; ++r) {
        const float za = acc1b[0][n][r] + ba[r];
        const float zb = acc1b[1][n][r] + bs[r];
        const float th = 1.f - 2.f / (1.f + __expf(2.f * za));
        const float sg = 1.f / (1.f + __expf(-zb));
        g4[r] = f2b(th * sg);
      }
      const int q2 = n * 16 + lh;
      const int ci = (o0 >> 3) ^ (q2 & 7);
      *(bf16x4*)(G + q2 * 256 + ci * 16 + (o0 & 7) * 2) = g4;
    }
  }
  __syncthreads();

  f32x4 s4vP[4];
  {
    f32x4 acc2[4];
    #pragma unroll
    for (int n = 0; n < 4; ++n) acc2[n] = fz;
    const short* wol2 = wob + (size_t)(L + 1) * 16384;
    #pragma unroll
    for (int ks = 0; ks < 4; ++ks) {
      const bf16x8 a = *(const bf16x8*)(wol2 + (16 * w + lh) * 128 + ks * 32 + lq * 8);
      #pragma unroll
      for (int n = 0; n < 4; ++n) {
        const int q2 = n * 16 + lh;
        const int ci = (ks * 4 + lq) ^ (q2 & 7);
        const bf16x8 bb = *(const bf16x8*)(G + q2 * 256 + ci * 16);
        acc2[n] = mfma16(a, bb, acc2[n]);
      }
    }
    float bo[4];
    #pragma unroll
    for (int r = 0; r < 4; ++r) bo[r] = b_out[(L + 1) * 128 + o0 + r];
    #pragma unroll
    for (int n = 0; n < 4; ++n) {
      const int q = 16 + n * 16 + lh;
      const int ci = (o0 >> 3) ^ (q & 7);
      const bf16x4 h4 = *(const bf16x4*)(ldsY + q * 256 + ci * 16 + (o0 & 7) * 2);
      f32x4 s4, xn;
      #pragma unroll
      for (int r = 0; r < 4; ++r) {
        s4[r] = acc2[n][r] + bo[r];
        xn[r] = s4[r] + b2f(h4[r]);
      }
      s4vP[n] = s4;
      bf16x4 x4;
      #pragma unroll
      for (int r = 0; r < 4; ++r) x4[r] = f2b(xn[r]);
      *(bf16x4*)(ldsY + q * 256 + ci * 16 + (o0 & 7) * 2) = x4;
    }
  }
  __syncthreads();

  #pragma unroll
  for (int n = 0; n < 4; ++n) {
    const int tt = n * 16 + lh;
    #pragma unroll
    for (int r = 0; r < 4; ++r) {
      const int o  = o0 + r;
      const int lg = tt >> 2;
      const int pg = (lg & 8) | ((lg ^ (o & 7)) & 7);
      *(float*)(S + o * 256 + pg * 16 + (tt & 3) * 4) = s4vP[n][r];
    }
  }
  __syncthreads();

  {
    float* skipBase = out + XOFFS + ((size_t)(((L + 1) * NB + b) * NC)) * NT + t0;
    const int j8 = tid & 7;
    #pragma unroll
    for (int half = 0; half < 2; ++half) {
      const int o = half * 64 + (tid >> 3);
      #pragma unroll
      for (int k = 0; k < 2; ++k) {
        const int pg = (k * 8) | ((j8 ^ (o & 7)) & 7);
        const f32x4 v = *(const f32x4*)(S + o * 256 + pg * 16);
        __builtin_nontemporal_store(v, (f32x4*)(skipBase + (size_t)o * NT + j8 * 4 + k * 32));
      }
    }
    char* dstBase = (char*)xbout + ((size_t)(b * NT + t0)) * 256;
    #pragma unroll
    for (int k = 0; k < 2; ++k) {
      const int idx = k * 512 + tid;
      const int r = idx >> 4, pcol = idx & 15;
      *(f32x4*)(dstBase + r * 256 + pcol * 16) =
          *(const f32x4*)(ldsY + (16 + r) * 256 + pcol * 16);
    }
  }
}

__global__ __launch_bounds__(512, 4)
void wavenet_pair6(const short* __restrict__ wcb,
                   const float* __restrict__ b_conv,
                   const short* __restrict__ wob,
                   const float* __restrict__ b_out,
                   const short* __restrict__ xbin,
                   short* __restrict__ xbout,
                   float* __restrict__ out,
                   int L, int d1, int d2)
{
  __shared__ char ldsY[96 * 256];
  __shared__ char ldsXG[112 * 256 + 96 * 256];
  char* X = ldsXG;
  char* G = ldsXG + 112 * 256;
  char* S = ldsXG;

  const int tid = threadIdx.x;
  const int w = tid >> 6, l = tid & 63, lh = l & 15, lq = l >> 4;
  const int o0 = 16 * w + lq * 4;
  const int uid = (blockIdx.x & 7) * 64 + (blockIdx.x >> 3);
  const int b   = uid >> 7;
  const int t0  = (uid & 127) * 64;
  const bool zhalo = (t0 == 0);
  const f32x4 fz = {0.f, 0.f, 0.f, 0.f};
  const size_t XOFFS = (size_t)NB * NC * NT;

  if (!zhalo) {
    const char* src = (const char*)xbin + ((size_t)(b * NT + t0 - 48)) * 256;
    #pragma unroll
    for (int k = 0; k < 4; ++k) {
      const int off = k * 8192 + tid * 16;
      if (off < 112 * 256) gl_lds16(src + off, X + off);
    }
  } else {
    if (tid * 16 < 12288) {
      bf16x8 z = {0, 0, 0, 0, 0, 0, 0, 0};
      *(bf16x8*)(X + tid * 16) = z;
      if (tid * 16 + 8192 < 12288) *(bf16x8*)(X + tid * 16 + 8192) = z;
    }
    const char* src = (const char*)xbin + ((size_t)(b * NT)) * 256;
    gl_lds16(src + tid * 16,        X + 12288 + tid * 16);
    gl_lds16(src + tid * 16 + 8192, X + 12288 + tid * 16 + 8192);
  }
  __syncthreads();

  f32x4 acc1[2][6];
  #pragma unroll
  for (int mi = 0; mi < 2; ++mi)
    #pragma unroll
    for (int nn = 0; nn < 6; ++nn) acc1[mi][nn] = fz;
  {
    const short* wl = wcb + (size_t)L * 65536;
    #pragma unroll
    for (int ks = 0; ks < 8; ++ks) {
      const bf16x8 a0 = *(const bf16x8*)(wl + (16 * w + lh) * 256 + ks * 32 + lq * 8);
      const bf16x8 a1 = *(const bf16x8*)(wl + (128 + 16 * w + lh) * 256 + ks * 32 + lq * 8);
      const int dd = (ks < 4) ? d1 : 0;
      #pragma unroll
      for (int nn = 0; nn < 6; ++nn) {
        const int p = 16 + nn * 16 + lh - dd;
        const int ci = ((ks & 3) * 4 + lq) ^ (p & 7);
        const bf16x8 bb = *(const bf16x8*)(X + p * 256 + ci * 16);
        acc1[0][nn] = mfma16(a0, bb, acc1[0][nn]);
        acc1[1][nn] = mfma16(a1, bb, acc1[1][nn]);
      }
    }
  }
  {
    float ba[4], bs[4];
    #pragma unroll
    for (int r = 0; r < 4; ++r) {
      ba[r] = b_conv[L * 256 + o0 + r];
      bs[r] = b_conv[L * 256 + 128 + o0 + r];
    }
    #pragma unroll
    for (int nn = 0; nn < 6; ++nn) {
      bf16x4 g4;
      #pragma unroll
      for (int r = 0; r < 4; ++r) {
        const float za = acc1[0][nn][r] + ba[r];
        const float zb = acc1[1][nn][r] + bs[r];
        const float th = 1.f - 2.f / (1.f + __expf(2.f * za));
        const float sg = 1.f / (1.f + __expf(-zb));
        g4[r] = f2b(th * sg);
      }
      const int q = nn * 16 + lh;
      const int ci = (o0 >> 3) ^ (q & 7);
      *(bf16x4*)(G + q * 256 + ci * 16 + (o0 & 7) * 2) = g4;
    }
  }
  __syncthreads();

  f32x4 s4vL[4];
  {
    f32x4 acc2[6];
    #pragma unroll
    for (int nn = 0; nn < 6; ++nn) acc2[nn] = fz;
    const short* wol = wob + (size_t)L * 16384;
    #pragma unroll
    for (int ks = 0; ks < 4; ++ks) {
      const bf16x8 a = *(const bf16x8*)(wol + (16 * w + lh) * 128 + ks * 32 + lq * 8);
      #pragma unroll
      for (int nn = 0; nn < 6; ++nn) {
        const int q = nn * 16 + lh;
        const int ci = (ks * 4 + lq) ^ (q & 7);
        const bf16x8 bb = *(const bf16x8*)(G + q * 256 + ci * 16);
        acc2[nn] = mfma16(a, bb, acc2[nn]);
      }
    }
    float bo[4];
    #pragma unroll
    for (int r = 0; r < 4; ++r) bo[r] = b_out[L * 128 + o0 + r];
    #pragma unroll
    for (int nn = 0; nn < 6; ++nn) {
      const int q = nn * 16 + lh;
      const int p = q + 16;
      const int ci = (o0 >> 3) ^ (q & 7);
      const bf16x4 h4 = *(const bf16x4*)(X + p * 256 + ci * 16 + (o0 & 7) * 2);
      f32x4 s4, xn;
      #pragma unroll
      for (int r = 0; r < 4; ++r) {
        s4[r] = acc2[nn][r] + bo[r];
        xn[r] = s4[r] + b2f(h4[r]);
      }
      if (nn >= 2) s4vL[nn - 2] = s4;
      bf16x4 x4;
      #pragma unroll
      for (int r = 0; r < 4; ++r) x4[r] = f2b(xn[r]);
      if (zhalo && nn < 2) { x4[0] = 0; x4[1] = 0; x4[2] = 0; x4[3] = 0; }
      *(bf16x4*)(ldsY + q * 256 + ci * 16 + (o0 & 7) * 2) = x4;
    }
  }
  __syncthreads();

  #pragma unroll
  for (int nn = 0; nn < 4; ++nn) {
    const int tt = nn * 16 + lh;
    #pragma unroll
    for (int r = 0; r < 4; ++r) {
      const int o  = o0 + r;
      const int lg = tt >> 2;
      const int pg = (lg & 8) | ((lg ^ (o & 7)) & 7);
      *(float*)(S + o * 256 + pg * 16 + (tt & 3) * 4) = s4vL[nn][r];
    }
  }
  __syncthreads();

  f32x4 acc1b[2][4];
  #pragma unroll
  for (int mi = 0; mi < 2; ++mi)
    #pragma unroll
    for (int n = 0; n < 4; ++n) acc1b[mi][n] = fz;
  {
    float* skipBase = out + XOFFS + ((size_t)((L * NB + b) * NC)) * NT + t0;
    const int j8 = tid & 7;
    #pragma unroll
    for (int half = 0; half < 2; ++half) {
      const int o = half * 64 + (tid >> 3);
      #pragma unroll
      for (int k = 0; k < 2; ++k) {
        const int pg = (k * 8) | ((j8 ^ (o & 7)) & 7);
        const f32x4 v = *(const f32x4*)(S + o * 256 + pg * 16);
        __builtin_nontemporal_store(v, (f32x4*)(skipBase + (size_t)o * NT + j8 * 4 + k * 32));
      }
    }
    const short* wl2 = wcb + (size_t)(L + 1) * 65536;
    #pragma unroll
    for (int ks = 0; ks < 8; ++ks) {
      const bf16x8 a0 = *(const bf16x8*)(wl2 + (16 * w + lh) * 256 + ks * 32 + lq * 8);
      const bf16x8 a1 = *(const bf16x8*)(wl2 + (128 + 16 * w + lh) * 256 + ks * 32 + lq * 8);
      const int dd = (ks < 4) ? d2 : 0;
      #pragma unroll
      for (int n = 0; n < 4; ++n) {
        const int qy = 32 + n * 16 + lh - dd;
        const int ci = ((ks & 3) * 4 + lq) ^ (qy & 7);
        const bf16x8 bb = *(const bf16x8*)(ldsY + qy * 256 + ci * 16);
        acc1b[0][n] = mfma16(a0, bb, acc1b[0][n]);
        acc1b[1][n] = mfma16(a1, bb, acc1b[1][n]);
      }
    }
  }
  __syncthreads();

  {
    float ba[4], bs[4];
    #pragma unroll
    for (int r = 0; r < 4; ++r) {
      ba[r] = b_conv[(L + 1) * 256 + o0 + r];
      bs[r] = b_conv[(L + 1) * 256 + 128 + o0 + r];
    }
    #pragma unroll
    for (int n = 0; n < 4; ++n) {
      bf16x4 g4;
      #pragma unroll
      for (int r = 0; r < 4; ++r) {
        const float za = acc1b[0][n][r] + ba[r];
        const float zb = acc1b[1][n][r] + bs[r];
        const float th = 1.f - 2.f / (1.f + __expf(2.f * za));
        const float sg = 1.f / (1.f + __expf(-zb));
        g4[r] = f2b(th * sg);
      }
      const int q2 = n * 16 + lh;
      const int ci = (o0 >> 3) ^ (q2 & 7);
      *(bf16x4*)(G + q2 * 256 + ci * 16 + (o0 & 7) * 2) = g4;
    }
  }
  __syncthreads();

  f32x4 s4vP[4];
  {
    f32x4 acc2[4];
    #pragma unroll
    for (int n = 0; n < 4; ++n) acc2[n] = fz;
    const short* wol2 = wob + (size_t)(L + 1) * 16384;
    #pragma unroll
    for (int ks = 0; ks < 4; ++ks) {
      const bf16x8 a = *(const bf16x8*)(wol2 + (16 * w + lh) * 128 + ks * 32 + lq * 8);
      #pragma unroll
      for (int n = 0; n < 4; ++n) {
        const int q2 = n * 16 + lh;
        const int ci = (ks * 4 + lq) ^ (q2 & 7);
        const bf16x8 bb = *(const bf16x8*)(G + q2 * 256 + ci * 16);
        acc2[n] = mfma16(a, bb, acc2[n]);
      }
    }
    float bo[4];
    #pragma unroll
    for (int r = 0; r < 4; ++r) bo[r] = b_out[(L + 1) * 128 + o0 + r];
    #pragma unroll
    for (int n = 0; n < 4; ++n) {
      const int q = 32 + n * 16 + lh;
      const int ci = (o0 >> 3) ^ (q & 7);
      const bf16x4 h4 = *(const bf16x4*)(ldsY + q * 256 + ci * 16 + (o0 & 7) * 2);
      f32x4 s4, xn;
      #pragma unroll
      for (int r = 0; r < 4; ++r) {
        s4[r] = acc2[n][r] + bo[r];
        xn[r] = s4[r] + b2f(h4[r]);
      }
      s4vP[n] = s4;
      bf16x4 x4;
      #pragma unroll
      for (int r = 0; r < 4; ++r) x4[r] = f2b(xn[r]);
      *(bf16x4*)(ldsY + q * 256 + ci * 16 + (o0 & 7) * 2) = x4;
    }
  }
  __syncthreads();

  #pragma unroll
  for (int n = 0; n < 4; ++n) {
    const int tt = n * 16 + lh;
    #pragma unroll
    for (int r = 0; r < 4; ++r) {
      const int o  = o0 + r;
      const int lg = tt >> 2;
      const int pg = (lg & 8) | ((lg ^ (o & 7)) & 7);
      *(float*)(S + o * 256 + pg * 16 + (tt & 3) * 4) = s4vP[n][r];
    }
  }
  __syncthreads();

  {
    float* skipBase = out + XOFFS + ((size_t)(((L + 1) * NB + b) * NC)) * NT + t0;
    const int j8 = tid & 7;
    #pragma unroll
    for (int half = 0; half < 2; ++half) {
      const int o = half * 64 + (tid >> 3);
      #pragma unroll
      for (int k = 0; k < 2; ++k) {
        const int pg = (k * 8) | ((j8 ^ (o & 7)) & 7);
        const f32x4 v = *(const f32x4*)(S + o * 256 + pg * 16);
        __builtin_nontemporal_store(v, (f32x4*)(skipBase + (size_t)o * NT + j8 * 4 + k * 32));
      }
    }
    char* dstBase = (char*)xbout + ((size_t)(b * NT + t0)) * 256;
    #pragma unroll
    for (int k = 0; k < 2; ++k) {
      const int idx = k * 512 + tid;
      const int r = idx >> 4, pcol = idx & 15;
      *(f32x4*)(dstBase + r * 256 + pcol * 16) =
          *(const f32x4*)(ldsY + (32 + r) * 256 + pcol * 16);
    }
  }
}

__global__ __launch_bounds__(512, 4)
void wavenet_layer(const short* __restrict__ wcb,
                   const float* __restrict__ b_conv,
                   const short* __restrict__ wob,
                   const float* __restrict__ b_out,
                   const short* __restrict__ xbin,
                   short* __restrict__ xbout,
                   float* __restrict__ out,
                   int layer, int dil, int last)
{
  __shared__ char ldsXC[TL * 256];
  __shared__ char ldsSP[TL * 256 + TL * GROWB];
  char* ldsXP = ldsSP;
  char* ldsG  = ldsSP + TL * 256;
  char* ldsS  = ldsSP;

  const int tid = threadIdx.x;
  const int w   = tid >> 6;
  const int l   = tid & 63;
  const int lh  = l & 15;
  const int lq  = l >> 4;
  const int o0  = 16 * w + lq * 4;
  const int uid = (blockIdx.x & 7) * 64 + (blockIdx.x >> 3);
  const int b   = uid >> 7;
  const int t0  = (uid & 127) * 64;

  {
    const char* xcg = (const char*)xbin + ((size_t)(b * NT + t0)) * 256;
    const int off = w * 2048 + l * 16;
    gl_lds16(xcg + off, ldsXC + off);
    gl_lds16(xcg + off + 1024, ldsXC + off + 1024);
  }
  if (t0 >= dil) {
    const char* xpg = (const char*)xbin + ((size_t)(b * NT + t0 - dil)) * 256;
    const int off = w * 2048 + l * 16;
    gl_lds16(xpg + off, ldsXP + off);
    gl_lds16(xpg + off + 1024, ldsXP + off + 1024);
  } else {
    const int row = tid >> 3, j8 = tid & 7;
    const int tp = t0 + row - dil;
    char* dst = ldsXP + row * 256;
    if (tp >= 0) {
      const char* src = (const char*)xbin + ((size_t)(b * NT + tp)) * 256;
      *(bf16x8*)(dst + j8 * 16)       = *(const bf16x8*)(src + j8 * 16);
      *(bf16x8*)(dst + j8 * 16 + 128) = *(const bf16x8*)(src + j8 * 16 + 128);
    } else {
      bf16x8 z = {0, 0, 0, 0, 0, 0, 0, 0};
      *(bf16x8*)(dst + j8 * 16)       = z;
      *(bf16x8*)(dst + j8 * 16 + 128) = z;
    }
  }
  __syncthreads();

  const f32x4 fz = {0.f, 0.f, 0.f, 0.f};
  f32x4 acc1[2][4];
  #pragma unroll
  for (int mi = 0; mi < 2; ++mi)
    #pragma unroll
    for (int n = 0; n < 4; ++n) acc1[mi][n] = fz;

  const short* wl = wcb + (size_t)layer * 65536;
  #pragma unroll
  for (int ks = 0; ks < 8; ++ks) {
    const bf16x8 a0 = *(const bf16x8*)(wl + (16 * w + lh) * 256 + ks * 32 + lq * 8);
    const bf16x8 a1 = *(const bf16x8*)(wl + (128 + 16 * w + lh) * 256 + ks * 32 + lq * 8);
    const char* base = (ks < 4) ? ldsXP : ldsXC;
    const int dd = (ks < 4) ? dil : 0;
    #pragma unroll
    for (int n = 0; n < 4; ++n) {
      const int tt = n * 16 + lh;
      const int ci = ((ks & 3) * 4 + lq) ^ ((tt - dd) & 7);
      const bf16x8 bb = *(const bf16x8*)(base + tt * 256 + ci * 16);
      acc1[0][n] = mfma16(a0, bb, acc1[0][n]);
      acc1[1][n] = mfma16(a1, bb, acc1[1][n]);
    }
  }

  {
    float ba[4], bs[4];
    #pragma unroll
    for (int r = 0; r < 4; ++r) {
      ba[r] = b_conv[layer * 256 + o0 + r];
      bs[r] = b_conv[layer * 256 + 128 + o0 + r];
    }
    #pragma unroll
    for (int n = 0; n < 4; ++n) {
      bf16x4 g4;
      #pragma unroll
      for (int r = 0; r < 4; ++r) {
        const float za = acc1[0][n][r] + ba[r];
        const float zb = acc1[1][n][r] + bs[r];
        const float th = 1.f - 2.f / (1.f + __expf(2.f * za));
        const float sg = 1.f / (1.f + __expf(-zb));
        g4[r] = f2b(th * sg);
      }
      const int tt = n * 16 + lh;
      *(bf16x4*)(ldsG + tt * GROWB + o0 * 2) = g4;
    }
  }
  __syncthreads();

  f32x4 acc2[4];
  #pragma unroll
  for (int n = 0; n < 4; ++n) acc2[n] = fz;
  const short* wol = wob + (size_t)layer * 16384;
  #pragma unroll
  for (int ks = 0; ks < 4; ++ks) {
    const bf16x8 a = *(const bf16x8*)(wol + (16 * w + lh) * 128 + ks * 32 + lq * 8);
    #pragma unroll
    for (int n = 0; n < 4; ++n) {
      const int tt = n * 16 + lh;
      const bf16x8 bb = *(const bf16x8*)(ldsG + tt * GROWB + ks * 64 + lq * 16);
      acc2[n] = mfma16(a, bb, acc2[n]);
    }
  }
  __syncthreads();

  f32x4 xn4[4];
  {
    float bo[4];
    #pragma unroll
    for (int r = 0; r < 4; ++r) bo[r] = b_out[layer * 128 + o0 + r];
    #pragma unroll
    for (int n = 0; n < 4; ++n) {
      const int tt = n * 16 + lh;
      const int ci = (o0 >> 3) ^ (tt & 7);
      const bf16x4 h4 = *(const bf16x4*)(ldsXC + tt * 256 + ci * 16 + (o0 & 7) * 2);
      f32x4 s4, xn;
      #pragma unroll
      for (int r = 0; r < 4; ++r) {
        s4[r] = acc2[n][r] + bo[r];
        xn[r] = s4[r] + b2f(h4[r]);
      }
      #pragma unroll
      for (int r = 0; r < 4; ++r) {
        const int o  = o0 + r;
        const int lg = tt >> 2;
        const int pg = (lg & 8) | ((lg ^ (o & 7)) & 7);
        *(float*)(ldsS + o * 256 + pg * 16 + (tt & 3) * 4) = s4[r];
      }
      if (!last) {
        bf16x4 x4;
        #pragma unroll
        for (int r = 0; r < 4; ++r) x4[r] = f2b(xn[r]);
        *(bf16x4*)(ldsXC + tt * 256 + ci * 16 + (o0 & 7) * 2) = x4;
      } else {
        xn4[n] = xn;
      }
    }
  }
  __syncthreads();

  const size_t XOFFS = (size_t)NB * NC * NT;
  {
    float* skipBase = out + XOFFS + ((size_t)((layer * NB + b) * NC)) * NT + t0;
    const int j8 = tid & 7;
    #pragma unroll
    for (int half = 0; half < 2; ++half) {
      const int o = half * 64 + (tid >> 3);
      #pragma unroll
      for (int k = 0; k < 2; ++k) {
        const int pg = (k * 8) | ((j8 ^ (o & 7)) & 7);
        const f32x4 v = *(const f32x4*)(ldsS + o * 256 + pg * 16);
        __builtin_nontemporal_store(v, (f32x4*)(skipBase + (size_t)o * NT + j8 * 4 + k * 32));
      }
    }
  }
  if (!last) {
    char* dstBase = (char*)xbout + ((size_t)(b * NT + t0)) * 256;
    #pragma unroll
    for (int k = 0; k < 2; ++k) {
      const int idx = k * 512 + tid;
      const int r = idx >> 4, p = idx & 15;
      *(f32x4*)(dstBase + r * 256 + p * 16) = *(const f32x4*)(ldsXC + r * 256 + p * 16);
    }
  } else {
    {
      #pragma unroll
      for (int n = 0; n < 4; ++n) {
        const int tt = n * 16 + lh;
        #pragma unroll
        for (int r = 0; r < 4; ++r)
          *(short*)(ldsXC + (o0 + r) * 128 + tt * 2) = f2b(xn4[n][r]);
      }
    }
    __syncthreads();
    float* xBase = out + ((size_t)(b * NC)) * NT + t0;
    const int j16 = tid & 15;
    #pragma unroll
    for (int k = 0; k < 4; ++k) {
      const int o = k * 32 + (tid >> 4);
      const bf16x4 v = *(const bf16x4*)(ldsXC + o * 128 + j16 * 8);
      f32x4 f;
      #pragma unroll
      for (int r = 0; r < 4; ++r) f[r] = b2f(v[r]);
      __builtin_nontemporal_store(f, (f32x4*)(xBase + (size_t)o * NT + j16 * 4));
    }
  }
}

extern "C" void kernel_launch(void* const* d_in, const int* in_sizes, int n_in,
                              void* d_out, int out_size, void* d_ws, size_t ws_size,
                              hipStream_t stream) {
  const float* x      = (const float*)d_in[0];
  const float* w_conv = (const float*)d_in[1];
  const float* b_conv = (const float*)d_in[2];
  const float* w_out  = (const float*)d_in[3];
  const float* b_out  = (const float*)d_in[4];
  float* out = (float*)d_out;

  const size_t XTN = (size_t)NB * NT * NC;
  short* xb[2];
  xb[0] = (short*)d_ws;
  xb[1] = xb[0] + XTN;
  short* wcb = xb[1] + XTN;
  short* wob = wcb + CONVN;
  int*   flags = (int*)(wob + WOUTN);
  int*   acks  = flags + FLAGN;

  hipMemsetAsync(flags, 0, 2 * FLAGN * sizeof(int), stream);
  prep<<<dim3(PACKB + TRANB), 256, 0, stream>>>(x, w_conv, w_out, xb[0], wcb, wob);

  short* xb0 = xb[0];
  short* xb1 = xb[1];
  void* args[] = {(void*)&wcb, (void*)&b_conv, (void*)&wob, (void*)&b_out,
                  (void*)&xb0, (void*)&xb1, (void*)&out,
                  (void*)&flags, (void*)&acks};
  hipError_t e = hipLaunchCooperativeKernel((void*)wavenet_persist, dim3(512),
                                            dim3(512), args, 0, stream);
  if (e == hipSuccess) return;

  // ---- fallback: R17 multi-launch chain (bit-identical output) ----
  int cur = 0;
  wavenet_pair<<<dim3(512), 512, 0, stream>>>(wcb, b_conv, wob, b_out,
                                              xb[cur], xb[cur ^ 1], out, 0, 1, 2);
  cur ^= 1;
  wavenet_pair<<<dim3(512), 512, 0, stream>>>(wcb, b_conv, wob, b_out,
                                              xb[cur], xb[cur ^ 1], out, 2, 4, 8);
  cur ^= 1;
  wavenet_pair6<<<dim3(512), 512, 0, stream>>>(wcb, b_conv, wob, b_out,
                                               xb[cur], xb[cur ^ 1], out, 4, 16, 32);
  cur ^= 1;
  for (int i = 6; i <= 9; ++i) {
    wavenet_layer<<<dim3(512), 512, 0, stream>>>(
        wcb, b_conv, wob, b_out, xb[cur], xb[cur ^ 1], out, i, 1 << i, 0);
    cur ^= 1;
  }
  wavenet_pair<<<dim3(512), 512, 0, stream>>>(wcb, b_conv, wob, b_out,
                                              xb[cur], xb[cur ^ 1], out, 10, 1, 2);
  cur ^= 1;
  wavenet_pair<<<dim3(512), 512, 0, stream>>>(wcb, b_conv, wob, b_out,
                                              xb[cur], xb[cur ^ 1], out, 12, 4, 8);
  cur ^= 1;
  wavenet_pair6<<<dim3(512), 512, 0, stream>>>(wcb, b_conv, wob, b_out,
                                               xb[cur], xb[cur ^ 1], out, 14, 16, 32);
  cur ^= 1;
  for (int i = 16; i <= 19; ++i) {
    wavenet_layer<<<dim3(512), 512, 0, stream>>>(
        wcb, b_conv, wob, b_out, xb[cur], xb[cur ^ 1], out, i, 1 << (i - 10),
        (i == 19) ? 1 : 0);
    cur ^= 1;
  }
}

// Round 20
// 344.438 us; speedup vs baseline: 1.9478x; 1.9478x over previous
//
#include <hip/hip_runtime.h>
#include <hip/hip_bf16.h>
#include <stdint.h>

using f32x4  = __attribute__((ext_vector_type(4))) float;
using bf16x8 = __attribute__((ext_vector_type(8))) short;
using bf16x4 = __attribute__((ext_vector_type(4))) short;

#define NB   4
#define NC   128
#define NT   8192
#define TL   64
#define NLAYER 20
#define GROWB 272
#define CONVN (NLAYER * 256 * 256)
#define WOUTN (NLAYER * 128 * 128)
#define PACKB ((CONVN + WOUTN + 255) / 256)
#define TRANB ((NT / 64) * (NC / 64) * NB)

__device__ __forceinline__ short f2b(float f) {
  union { float f; unsigned u; } v; v.f = f;
  unsigned r = v.u + 0x7FFFu + ((v.u >> 16) & 1u);   // RNE
  return (short)(r >> 16);
}

__device__ __forceinline__ float b2f(short s) {
  union { unsigned u; float f; } v;
  v.u = ((unsigned)(unsigned short)s) << 16;
  return v.f;
}

__device__ __forceinline__ f32x4 mfma16(bf16x8 a, bf16x8 b, f32x4 c) {
  return __builtin_amdgcn_mfma_f32_16x16x32_bf16(a, b, c, 0, 0, 0);
}

__device__ __forceinline__ void gl_lds16(const void* g, void* l) {
  __builtin_amdgcn_global_load_lds(
      (const __attribute__((address_space(1))) void*)g,
      (__attribute__((address_space(3))) void*)l, 16, 0, 0);
}

// Fused prep: blocks [0, PACKB) pack weights; blocks [PACKB, PACKB+TRANB)
// transpose x -> xtb (bf16 swizzled 256B rows, 16B groups XOR t&7).
__global__ void prep(const float* __restrict__ x,
                     const float* __restrict__ w_conv,
                     const float* __restrict__ w_out,
                     short* __restrict__ xtb,
                     short* __restrict__ wcb, short* __restrict__ wob) {
  __shared__ float tile[64][65];
  if (blockIdx.x < PACKB) {
    const int idx = blockIdx.x * 256 + threadIdx.x;
    if (idx < CONVN) {
      const int k = idx & 255, o = (idx >> 8) & 255, lyr = idx >> 16;
      const int tap = k >> 7, c = k & 127;
      wcb[idx] = f2b(w_conv[(((size_t)lyr * 256 + o) * 128 + c) * 2 + tap]);
    } else if (idx < CONVN + WOUTN) {
      const int j = idx - CONVN;
      wob[j] = f2b(w_out[j]);
    }
    return;
  }
  const int bid2 = blockIdx.x - PACKB;
  const int t0 = (bid2 & 127) * 64;
  const int c0 = ((bid2 >> 7) & 1) * 64;
  const int b  = bid2 >> 8;
  const int lane = threadIdx.x & 63;
  const int r4   = threadIdx.x >> 6;
  #pragma unroll
  for (int i = 0; i < 16; ++i) {
    const int cl = i * 4 + r4;
    tile[cl][lane] = x[((size_t)(b * NC + c0 + cl)) * NT + t0 + lane];
  }
  __syncthreads();
  #pragma unroll
  for (int it = 0; it < 2; ++it) {
    const int idx = it * 256 + threadIdx.x;
    const int r  = idx >> 3;
    const int gi = idx & 7;
    bf16x8 v;
    #pragma unroll
    for (int jj = 0; jj < 8; ++jj) v[jj] = f2b(tile[gi * 8 + jj][r]);
    const int t = t0 + r;
    const int ci = ((c0 >> 3) + gi) ^ (t & 7);
    *(bf16x8*)((char*)xtb + ((size_t)(b * NT + t)) * 256 + ci * 16) = v;
  }
}

// ---- fused pair (L, L+1), d1 <= 8, d2 <= 16. X: 88 rows [t0-24, t0+64). ----
__global__ __launch_bounds__(512, 4)
void wavenet_pair(const short* __restrict__ wcb,
                  const float* __restrict__ b_conv,
                  const short* __restrict__ wob,
                  const float* __restrict__ b_out,
                  const short* __restrict__ xbin,
                  short* __restrict__ xbout,
                  float* __restrict__ out,
                  int L, int d1, int d2)
{
  __shared__ char ldsY[80 * 256];                  // 20480
  __shared__ char ldsXG[88 * 256 + 80 * 256];      // X 22528 + G 20480
  char* X = ldsXG;
  char* G = ldsXG + 88 * 256;
  char* S = ldsXG;                                 // [0, 32768)

  const int tid = threadIdx.x;
  const int w = tid >> 6, l = tid & 63, lh = l & 15, lq = l >> 4;
  const int o0 = 16 * w + lq * 4;
  const int uid = (blockIdx.x & 7) * 64 + (blockIdx.x >> 3);
  const int b   = uid >> 7;
  const int t0  = (uid & 127) * 64;
  const bool zhalo = (t0 == 0);
  const f32x4 fz = {0.f, 0.f, 0.f, 0.f};
  const size_t XOFFS = (size_t)NB * NC * NT;

  if (!zhalo) {
    const char* src = (const char*)xbin + ((size_t)(b * NT + t0 - 24)) * 256;
    #pragma unroll
    for (int k = 0; k < 3; ++k) {
      const int off = k * 8192 + tid * 16;
      if (off < 88 * 256) gl_lds16(src + off, X + off);
    }
  } else {
    if (tid * 16 < 6144) {
      bf16x8 z = {0, 0, 0, 0, 0, 0, 0, 0};
      *(bf16x8*)(X + tid * 16) = z;
    }
    const char* src = (const char*)xbin + ((size_t)(b * NT)) * 256;
    gl_lds16(src + tid * 16,        X + 6144 + tid * 16);
    gl_lds16(src + tid * 16 + 8192, X + 6144 + tid * 16 + 8192);
  }
  __syncthreads();                                           // B1

  f32x4 acc1[2][5];
  #pragma unroll
  for (int mi = 0; mi < 2; ++mi)
    #pragma unroll
    for (int nn = 0; nn < 5; ++nn) acc1[mi][nn] = fz;
  {
    const short* wl = wcb + (size_t)L * 65536;
    #pragma unroll
    for (int ks = 0; ks < 8; ++ks) {
      const bf16x8 a0 = *(const bf16x8*)(wl + (16 * w + lh) * 256 + ks * 32 + lq * 8);
      const bf16x8 a1 = *(const bf16x8*)(wl + (128 + 16 * w + lh) * 256 + ks * 32 + lq * 8);
      const int dd = (ks < 4) ? d1 : 0;
      #pragma unroll
      for (int nn = 0; nn < 5; ++nn) {
        const int p = 8 + nn * 16 + lh - dd;
        const int ci = ((ks & 3) * 4 + lq) ^ (p & 7);
        const bf16x8 bb = *(const bf16x8*)(X + p * 256 + ci * 16);
        acc1[0][nn] = mfma16(a0, bb, acc1[0][nn]);
        acc1[1][nn] = mfma16(a1, bb, acc1[1][nn]);
      }
    }
  }
  {
    float ba[4], bs[4];
    #pragma unroll
    for (int r = 0; r < 4; ++r) {
      ba[r] = b_conv[L * 256 + o0 + r];
      bs[r] = b_conv[L * 256 + 128 + o0 + r];
    }
    #pragma unroll
    for (int nn = 0; nn < 5; ++nn) {
      bf16x4 g4;
      #pragma unroll
      for (int r = 0; r < 4; ++r) {
        const float za = acc1[0][nn][r] + ba[r];
        const float zb = acc1[1][nn][r] + bs[r];
        const float th = 1.f - 2.f / (1.f + __expf(2.f * za));
        const float sg = 1.f / (1.f + __expf(-zb));
        g4[r] = f2b(th * sg);
      }
      const int q = nn * 16 + lh;
      const int ci = (o0 >> 3) ^ (q & 7);
      *(bf16x4*)(G + q * 256 + ci * 16 + (o0 & 7) * 2) = g4;
    }
  }
  __syncthreads();                                           // B2

  f32x4 s4vL[4];
  {
    f32x4 acc2[5];
    #pragma unroll
    for (int nn = 0; nn < 5; ++nn) acc2[nn] = fz;
    const short* wol = wob + (size_t)L * 16384;
    #pragma unroll
    for (int ks = 0; ks < 4; ++ks) {
      const bf16x8 a = *(const bf16x8*)(wol + (16 * w + lh) * 128 + ks * 32 + lq * 8);
      #pragma unroll
      for (int nn = 0; nn < 5; ++nn) {
        const int q = nn * 16 + lh;
        const int ci = (ks * 4 + lq) ^ (q & 7);
        const bf16x8 bb = *(const bf16x8*)(G + q * 256 + ci * 16);
        acc2[nn] = mfma16(a, bb, acc2[nn]);
      }
    }
    float bo[4];
    #pragma unroll
    for (int r = 0; r < 4; ++r) bo[r] = b_out[L * 128 + o0 + r];
    #pragma unroll
    for (int nn = 0; nn < 5; ++nn) {
      const int q = nn * 16 + lh;
      const int p = q + 8;
      const int ci = (o0 >> 3) ^ (q & 7);
      const bf16x4 h4 = *(const bf16x4*)(X + p * 256 + ci * 16 + (o0 & 7) * 2);
      f32x4 s4, xn;
      #pragma unroll
      for (int r = 0; r < 4; ++r) {
        s4[r] = acc2[nn][r] + bo[r];
        xn[r] = s4[r] + b2f(h4[r]);
      }
      if (nn >= 1) s4vL[nn - 1] = s4;
      bf16x4 x4;
      #pragma unroll
      for (int r = 0; r < 4; ++r) x4[r] = f2b(xn[r]);
      if (zhalo && nn == 0) { x4[0] = 0; x4[1] = 0; x4[2] = 0; x4[3] = 0; }
      *(bf16x4*)(ldsY + q * 256 + ci * 16 + (o0 & 7) * 2) = x4;
    }
  }
  __syncthreads();                                           // B3

  #pragma unroll
  for (int nn = 0; nn < 4; ++nn) {
    const int tt = nn * 16 + lh;
    #pragma unroll
    for (int r = 0; r < 4; ++r) {
      const int o  = o0 + r;
      const int lg = tt >> 2;
      const int pg = (lg & 8) | ((lg ^ (o & 7)) & 7);
      *(float*)(S + o * 256 + pg * 16 + (tt & 3) * 4) = s4vL[nn][r];
    }
  }
  __syncthreads();                                           // B4

  f32x4 acc1b[2][4];
  #pragma unroll
  for (int mi = 0; mi < 2; ++mi)
    #pragma unroll
    for (int n = 0; n < 4; ++n) acc1b[mi][n] = fz;
  {
    float* skipBase = out + XOFFS + ((size_t)((L * NB + b) * NC)) * NT + t0;
    const int j8 = tid & 7;
    #pragma unroll
    for (int half = 0; half < 2; ++half) {
      const int o = half * 64 + (tid >> 3);
      #pragma unroll
      for (int k = 0; k < 2; ++k) {
        const int pg = (k * 8) | ((j8 ^ (o & 7)) & 7);
        const f32x4 v = *(const f32x4*)(S + o * 256 + pg * 16);
        __builtin_nontemporal_store(v, (f32x4*)(skipBase + (size_t)o * NT + j8 * 4 + k * 32));
      }
    }
    const short* wl2 = wcb + (size_t)(L + 1) * 65536;
    #pragma unroll
    for (int ks = 0; ks < 8; ++ks) {
      const bf16x8 a0 = *(const bf16x8*)(wl2 + (16 * w + lh) * 256 + ks * 32 + lq * 8);
      const bf16x8 a1 = *(const bf16x8*)(wl2 + (128 + 16 * w + lh) * 256 + ks * 32 + lq * 8);
      const int dd = (ks < 4) ? d2 : 0;
      #pragma unroll
      for (int n = 0; n < 4; ++n) {
        const int qy = 16 + n * 16 + lh - dd;
        const int ci = ((ks & 3) * 4 + lq) ^ (qy & 7);
        const bf16x8 bb = *(const bf16x8*)(ldsY + qy * 256 + ci * 16);
        acc1b[0][n] = mfma16(a0, bb, acc1b[0][n]);
        acc1b[1][n] = mfma16(a1, bb, acc1b[1][n]);
      }
    }
  }
  __syncthreads();                                           // B5

  {
    float ba[4], bs[4];
    #pragma unroll
    for (int r = 0; r < 4; ++r) {
      ba[r] = b_conv[(L + 1) * 256 + o0 + r];
      bs[r] = b_conv[(L + 1) * 256 + 128 + o0 + r];
    }
    #pragma unroll
    for (int n = 0; n < 4; ++n) {
      bf16x4 g4;
      #pragma unroll
      for (int r = 0; r < 4; ++r) {
        const float za = acc1b[0][n][r] + ba[r];
        const float zb = acc1b[1][n][r] + bs[r];
        const float th = 1.f - 2.f / (1.f + __expf(2.f * za));
        const float sg = 1.f / (1.f + __expf(-zb));
        g4[r] = f2b(th * sg);
      }
      const int q2 = n * 16 + lh;
      const int ci = (o0 >> 3) ^ (q2 & 7);
      *(bf16x4*)(G + q2 * 256 + ci * 16 + (o0 & 7) * 2) = g4;
    }
  }
  __syncthreads();                                           // B6

  f32x4 s4vP[4];
  {
    f32x4 acc2[4];
    #pragma unroll
    for (int n = 0; n < 4; ++n) acc2[n] = fz;
    const short* wol2 = wob + (size_t)(L + 1) * 16384;
    #pragma unroll
    for (int ks = 0; ks < 4; ++ks) {
      const bf16x8 a = *(const bf16x8*)(wol2 + (16 * w + lh) * 128 + ks * 32 + lq * 8);
      #pragma unroll
      for (int n = 0; n < 4; ++n) {
        const int q2 = n * 16 + lh;
        const int ci = (ks * 4 + lq) ^ (q2 & 7);
        const bf16x8 bb = *(const bf16x8*)(G + q2 * 256 + ci * 16);
        acc2[n] = mfma16(a, bb, acc2[n]);
      }
    }
    float bo[4];
    #pragma unroll
    for (int r = 0; r < 4; ++r) bo[r] = b_out[(L + 1) * 128 + o0 + r];
    #pragma unroll
    for (int n = 0; n < 4; ++n) {
      const int q = 16 + n * 16 + lh;
      const int ci = (o0 >> 3) ^ (q & 7);
      const bf16x4 h4 = *(const bf16x4*)(ldsY + q * 256 + ci * 16 + (o0 & 7) * 2);
      f32x4 s4, xn;
      #pragma unroll
      for (int r = 0; r < 4; ++r) {
        s4[r] = acc2[n][r] + bo[r];
        xn[r] = s4[r] + b2f(h4[r]);
      }
      s4vP[n] = s4;
      bf16x4 x4;
      #pragma unroll
      for (int r = 0; r < 4; ++r) x4[r] = f2b(xn[r]);
      *(bf16x4*)(ldsY + q * 256 + ci * 16 + (o0 & 7) * 2) = x4;
    }
  }
  __syncthreads();                                           // B7

  #pragma unroll
  for (int n = 0; n < 4; ++n) {
    const int tt = n * 16 + lh;
    #pragma unroll
    for (int r = 0; r < 4; ++r) {
      const int o  = o0 + r;
      const int lg = tt >> 2;
      const int pg = (lg & 8) | ((lg ^ (o & 7)) & 7);
      *(float*)(S + o * 256 + pg * 16 + (tt & 3) * 4) = s4vP[n][r];
    }
  }
  __syncthreads();                                           // B8

  {
    float* skipBase = out + XOFFS + ((size_t)(((L + 1) * NB + b) * NC)) * NT + t0;
    const int j8 = tid & 7;
    #pragma unroll
    for (int half = 0; half < 2; ++half) {
      const int o = half * 64 + (tid >> 3);
      #pragma unroll
      for (int k = 0; k < 2; ++k) {
        const int pg = (k * 8) | ((j8 ^ (o & 7)) & 7);
        const f32x4 v = *(const f32x4*)(S + o * 256 + pg * 16);
        __builtin_nontemporal_store(v, (f32x4*)(skipBase + (size_t)o * NT + j8 * 4 + k * 32));
      }
    }
    char* dstBase = (char*)xbout + ((size_t)(b * NT + t0)) * 256;
    #pragma unroll
    for (int k = 0; k < 2; ++k) {
      const int idx = k * 512 + tid;
      const int r = idx >> 4, pcol = idx & 15;
      *(f32x4*)(dstBase + r * 256 + pcol * 16) =
          *(const f32x4*)(ldsY + (16 + r) * 256 + pcol * 16);
    }
  }
}

// ---- fused pair variant B (L, L+1), d1 <= 16, d2 <= 32. X: 112 rows. ----
__global__ __launch_bounds__(512, 4)
void wavenet_pair6(const short* __restrict__ wcb,
                   const float* __restrict__ b_conv,
                   const short* __restrict__ wob,
                   const float* __restrict__ b_out,
                   const short* __restrict__ xbin,
                   short* __restrict__ xbout,
                   float* __restrict__ out,
                   int L, int d1, int d2)
{
  __shared__ char ldsY[96 * 256];
  __shared__ char ldsXG[112 * 256 + 96 * 256];   // X 28672 + G 24576
  char* X = ldsXG;
  char* G = ldsXG + 112 * 256;
  char* S = ldsXG;

  const int tid = threadIdx.x;
  const int w = tid >> 6, l = tid & 63, lh = l & 15, lq = l >> 4;
  const int o0 = 16 * w + lq * 4;
  const int uid = (blockIdx.x & 7) * 64 + (blockIdx.x >> 3);
  const int b   = uid >> 7;
  const int t0  = (uid & 127) * 64;
  const bool zhalo = (t0 == 0);
  const f32x4 fz = {0.f, 0.f, 0.f, 0.f};
  const size_t XOFFS = (size_t)NB * NC * NT;

  if (!zhalo) {
    const char* src = (const char*)xbin + ((size_t)(b * NT + t0 - 48)) * 256;
    #pragma unroll
    for (int k = 0; k < 4; ++k) {
      const int off = k * 8192 + tid * 16;
      if (off < 112 * 256) gl_lds16(src + off, X + off);
    }
  } else {
    if (tid * 16 < 12288) {
      bf16x8 z = {0, 0, 0, 0, 0, 0, 0, 0};
      *(bf16x8*)(X + tid * 16) = z;
      if (tid * 16 + 8192 < 12288) *(bf16x8*)(X + tid * 16 + 8192) = z;
    }
    const char* src = (const char*)xbin + ((size_t)(b * NT)) * 256;
    gl_lds16(src + tid * 16,        X + 12288 + tid * 16);
    gl_lds16(src + tid * 16 + 8192, X + 12288 + tid * 16 + 8192);
  }
  __syncthreads();                                           // B1

  f32x4 acc1[2][6];
  #pragma unroll
  for (int mi = 0; mi < 2; ++mi)
    #pragma unroll
    for (int nn = 0; nn < 6; ++nn) acc1[mi][nn] = fz;
  {
    const short* wl = wcb + (size_t)L * 65536;
    #pragma unroll
    for (int ks = 0; ks < 8; ++ks) {
      const bf16x8 a0 = *(const bf16x8*)(wl + (16 * w + lh) * 256 + ks * 32 + lq * 8);
      const bf16x8 a1 = *(const bf16x8*)(wl + (128 + 16 * w + lh) * 256 + ks * 32 + lq * 8);
      const int dd = (ks < 4) ? d1 : 0;
      #pragma unroll
      for (int nn = 0; nn < 6; ++nn) {
        const int p = 16 + nn * 16 + lh - dd;
        const int ci = ((ks & 3) * 4 + lq) ^ (p & 7);
        const bf16x8 bb = *(const bf16x8*)(X + p * 256 + ci * 16);
        acc1[0][nn] = mfma16(a0, bb, acc1[0][nn]);
        acc1[1][nn] = mfma16(a1, bb, acc1[1][nn]);
      }
    }
  }
  {
    float ba[4], bs[4];
    #pragma unroll
    for (int r = 0; r < 4; ++r) {
      ba[r] = b_conv[L * 256 + o0 + r];
      bs[r] = b_conv[L * 256 + 128 + o0 + r];
    }
    #pragma unroll
    for (int nn = 0; nn < 6; ++nn) {
      bf16x4 g4;
      #pragma unroll
      for (int r = 0; r < 4; ++r) {
        const float za = acc1[0][nn][r] + ba[r];
        const float zb = acc1[1][nn][r] + bs[r];
        const float th = 1.f - 2.f / (1.f + __expf(2.f * za));
        const float sg = 1.f / (1.f + __expf(-zb));
        g4[r] = f2b(th * sg);
      }
      const int q = nn * 16 + lh;
      const int ci = (o0 >> 3) ^ (q & 7);
      *(bf16x4*)(G + q * 256 + ci * 16 + (o0 & 7) * 2) = g4;
    }
  }
  __syncthreads();                                           // B2

  f32x4 s4vL[4];
  {
    f32x4 acc2[6];
    #pragma unroll
    for (int nn = 0; nn < 6; ++nn) acc2[nn] = fz;
    const short* wol = wob + (size_t)L * 16384;
    #pragma unroll
    for (int ks = 0; ks < 4; ++ks) {
      const bf16x8 a = *(const bf16x8*)(wol + (16 * w + lh) * 128 + ks * 32 + lq * 8);
      #pragma unroll
      for (int nn = 0; nn < 6; ++nn) {
        const int q = nn * 16 + lh;
        const int ci = (ks * 4 + lq) ^ (q & 7);
        const bf16x8 bb = *(const bf16x8*)(G + q * 256 + ci * 16);
        acc2[nn] = mfma16(a, bb, acc2[nn]);
      }
    }
    float bo[4];
    #pragma unroll
    for (int r = 0; r < 4; ++r) bo[r] = b_out[L * 128 + o0 + r];
    #pragma unroll
    for (int nn = 0; nn < 6; ++nn) {
      const int q = nn * 16 + lh;
      const int p = q + 16;
      const int ci = (o0 >> 3) ^ (q & 7);
      const bf16x4 h4 = *(const bf16x4*)(X + p * 256 + ci * 16 + (o0 & 7) * 2);
      f32x4 s4, xn;
      #pragma unroll
      for (int r = 0; r < 4; ++r) {
        s4[r] = acc2[nn][r] + bo[r];
        xn[r] = s4[r] + b2f(h4[r]);
      }
      if (nn >= 2) s4vL[nn - 2] = s4;
      bf16x4 x4;
      #pragma unroll
      for (int r = 0; r < 4; ++r) x4[r] = f2b(xn[r]);
      if (zhalo && nn < 2) { x4[0] = 0; x4[1] = 0; x4[2] = 0; x4[3] = 0; }
      *(bf16x4*)(ldsY + q * 256 + ci * 16 + (o0 & 7) * 2) = x4;
    }
  }
  __syncthreads();                                           // B3

  #pragma unroll
  for (int nn = 0; nn < 4; ++nn) {
    const int tt = nn * 16 + lh;
    #pragma unroll
    for (int r = 0; r < 4; ++r) {
      const int o  = o0 + r;
      const int lg = tt >> 2;
      const int pg = (lg & 8) | ((lg ^ (o & 7)) & 7);
      *(float*)(S + o * 256 + pg * 16 + (tt & 3) * 4) = s4vL[nn][r];
    }
  }
  __syncthreads();                                           // B4

  f32x4 acc1b[2][4];
  #pragma unroll
  for (int mi = 0; mi < 2; ++mi)
    #pragma unroll
    for (int n = 0; n < 4; ++n) acc1b[mi][n] = fz;
  {
    float* skipBase = out + XOFFS + ((size_t)((L * NB + b) * NC)) * NT + t0;
    const int j8 = tid & 7;
    #pragma unroll
    for (int half = 0; half < 2; ++half) {
      const int o = half * 64 + (tid >> 3);
      #pragma unroll
      for (int k = 0; k < 2; ++k) {
        const int pg = (k * 8) | ((j8 ^ (o & 7)) & 7);
        const f32x4 v = *(const f32x4*)(S + o * 256 + pg * 16);
        __builtin_nontemporal_store(v, (f32x4*)(skipBase + (size_t)o * NT + j8 * 4 + k * 32));
      }
    }
    const short* wl2 = wcb + (size_t)(L + 1) * 65536;
    #pragma unroll
    for (int ks = 0; ks < 8; ++ks) {
      const bf16x8 a0 = *(const bf16x8*)(wl2 + (16 * w + lh) * 256 + ks * 32 + lq * 8);
      const bf16x8 a1 = *(const bf16x8*)(wl2 + (128 + 16 * w + lh) * 256 + ks * 32 + lq * 8);
      const int dd = (ks < 4) ? d2 : 0;
      #pragma unroll
      for (int n = 0; n < 4; ++n) {
        const int qy = 32 + n * 16 + lh - dd;
        const int ci = ((ks & 3) * 4 + lq) ^ (qy & 7);
        const bf16x8 bb = *(const bf16x8*)(ldsY + qy * 256 + ci * 16);
        acc1b[0][n] = mfma16(a0, bb, acc1b[0][n]);
        acc1b[1][n] = mfma16(a1, bb, acc1b[1][n]);
      }
    }
  }
  __syncthreads();                                           // B5

  {
    float ba[4], bs[4];
    #pragma unroll
    for (int r = 0; r < 4; ++r) {
      ba[r] = b_conv[(L + 1) * 256 + o0 + r];
      bs[r] = b_conv[(L + 1) * 256 + 128 + o0 + r];
    }
    #pragma unroll
    for (int n = 0; n < 4; ++n) {
      bf16x4 g4;
      #pragma unroll
      for (int r = 0; r < 4; ++r) {
        const float za = acc1b[0][n][r] + ba[r];
        const float zb = acc1b[1][n][r] + bs[r];
        const float th = 1.f - 2.f / (1.f + __expf(2.f * za));
        const float sg = 1.f / (1.f + __expf(-zb));
        g4[r] = f2b(th * sg);
      }
      const int q2 = n * 16 + lh;
      const int ci = (o0 >> 3) ^ (q2 & 7);
      *(bf16x4*)(G + q2 * 256 + ci * 16 + (o0 & 7) * 2) = g4;
    }
  }
  __syncthreads();                                           // B6

  f32x4 s4vP[4];
  {
    f32x4 acc2[4];
    #pragma unroll
    for (int n = 0; n < 4; ++n) acc2[n] = fz;
    const short* wol2 = wob + (size_t)(L + 1) * 16384;
    #pragma unroll
    for (int ks = 0; ks < 4; ++ks) {
      const bf16x8 a = *(const bf16x8*)(wol2 + (16 * w + lh) * 128 + ks * 32 + lq * 8);
      #pragma unroll
      for (int n = 0; n < 4; ++n) {
        const int q2 = n * 16 + lh;
        const int ci = (ks * 4 + lq) ^ (q2 & 7);
        const bf16x8 bb = *(const bf16x8*)(G + q2 * 256 + ci * 16);
        acc2[n] = mfma16(a, bb, acc2[n]);
      }
    }
    float bo[4];
    #pragma unroll
    for (int r = 0; r < 4; ++r) bo[r] = b_out[(L + 1) * 128 + o0 + r];
    #pragma unroll
    for (int n = 0; n < 4; ++n) {
      const int q = 32 + n * 16 + lh;
      const int ci = (o0 >> 3) ^ (q & 7);
      const bf16x4 h4 = *(const bf16x4*)(ldsY + q * 256 + ci * 16 + (o0 & 7) * 2);
      f32x4 s4, xn;
      #pragma unroll
      for (int r = 0; r < 4; ++r) {
        s4[r] = acc2[n][r] + bo[r];
        xn[r] = s4[r] + b2f(h4[r]);
      }
      s4vP[n] = s4;
      bf16x4 x4;
      #pragma unroll
      for (int r = 0; r < 4; ++r) x4[r] = f2b(xn[r]);
      *(bf16x4*)(ldsY + q * 256 + ci * 16 + (o0 & 7) * 2) = x4;
    }
  }
  __syncthreads();                                           // B7

  #pragma unroll
  for (int n = 0; n < 4; ++n) {
    const int tt = n * 16 + lh;
    #pragma unroll
    for (int r = 0; r < 4; ++r) {
      const int o  = o0 + r;
      const int lg = tt >> 2;
      const int pg = (lg & 8) | ((lg ^ (o & 7)) & 7);
      *(float*)(S + o * 256 + pg * 16 + (tt & 3) * 4) = s4vP[n][r];
    }
  }
  __syncthreads();                                           // B8

  {
    float* skipBase = out + XOFFS + ((size_t)(((L + 1) * NB + b) * NC)) * NT + t0;
    const int j8 = tid & 7;
    #pragma unroll
    for (int half = 0; half < 2; ++half) {
      const int o = half * 64 + (tid >> 3);
      #pragma unroll
      for (int k = 0; k < 2; ++k) {
        const int pg = (k * 8) | ((j8 ^ (o & 7)) & 7);
        const f32x4 v = *(const f32x4*)(S + o * 256 + pg * 16);
        __builtin_nontemporal_store(v, (f32x4*)(skipBase + (size_t)o * NT + j8 * 4 + k * 32));
      }
    }
    char* dstBase = (char*)xbout + ((size_t)(b * NT + t0)) * 256;
    #pragma unroll
    for (int k = 0; k < 2; ++k) {
      const int idx = k * 512 + tid;
      const int r = idx >> 4, pcol = idx & 15;
      *(f32x4*)(dstBase + r * 256 + pcol * 16) =
          *(const f32x4*)(ldsY + (32 + r) * 256 + pcol * 16);
    }
  }
}

// ---- single layer (R8 structure: S-bounce + NT full-line stores) ----
__global__ __launch_bounds__(512, 4)
void wavenet_layer(const short* __restrict__ wcb,
                   const float* __restrict__ b_conv,
                   const short* __restrict__ wob,
                   const float* __restrict__ b_out,
                   const short* __restrict__ xbin,
                   short* __restrict__ xbout,
                   float* __restrict__ out,
                   int layer, int dil, int last)
{
  __shared__ char ldsXC[TL * 256];
  __shared__ char ldsSP[TL * 256 + TL * GROWB];
  char* ldsXP = ldsSP;
  char* ldsG  = ldsSP + TL * 256;
  char* ldsS  = ldsSP;

  const int tid = threadIdx.x;
  const int w   = tid >> 6;
  const int l   = tid & 63;
  const int lh  = l & 15;
  const int lq  = l >> 4;
  const int o0  = 16 * w + lq * 4;
  const int uid = (blockIdx.x & 7) * 64 + (blockIdx.x >> 3);
  const int b   = uid >> 7;
  const int t0  = (uid & 127) * 64;

  {
    const char* xcg = (const char*)xbin + ((size_t)(b * NT + t0)) * 256;
    const int off = w * 2048 + l * 16;
    gl_lds16(xcg + off, ldsXC + off);
    gl_lds16(xcg + off + 1024, ldsXC + off + 1024);
  }
  if (t0 >= dil) {
    const char* xpg = (const char*)xbin + ((size_t)(b * NT + t0 - dil)) * 256;
    const int off = w * 2048 + l * 16;
    gl_lds16(xpg + off, ldsXP + off);
    gl_lds16(xpg + off + 1024, ldsXP + off + 1024);
  } else {
    const int row = tid >> 3, j8 = tid & 7;
    const int tp = t0 + row - dil;
    char* dst = ldsXP + row * 256;
    if (tp >= 0) {
      const char* src = (const char*)xbin + ((size_t)(b * NT + tp)) * 256;
      *(bf16x8*)(dst + j8 * 16)       = *(const bf16x8*)(src + j8 * 16);
      *(bf16x8*)(dst + j8 * 16 + 128) = *(const bf16x8*)(src + j8 * 16 + 128);
    } else {
      bf16x8 z = {0, 0, 0, 0, 0, 0, 0, 0};
      *(bf16x8*)(dst + j8 * 16)       = z;
      *(bf16x8*)(dst + j8 * 16 + 128) = z;
    }
  }
  __syncthreads();

  const f32x4 fz = {0.f, 0.f, 0.f, 0.f};
  f32x4 acc1[2][4];
  #pragma unroll
  for (int mi = 0; mi < 2; ++mi)
    #pragma unroll
    for (int n = 0; n < 4; ++n) acc1[mi][n] = fz;

  const short* wl = wcb + (size_t)layer * 65536;
  #pragma unroll
  for (int ks = 0; ks < 8; ++ks) {
    const bf16x8 a0 = *(const bf16x8*)(wl + (16 * w + lh) * 256 + ks * 32 + lq * 8);
    const bf16x8 a1 = *(const bf16x8*)(wl + (128 + 16 * w + lh) * 256 + ks * 32 + lq * 8);
    const char* base = (ks < 4) ? ldsXP : ldsXC;
    const int dd = (ks < 4) ? dil : 0;
    #pragma unroll
    for (int n = 0; n < 4; ++n) {
      const int tt = n * 16 + lh;
      const int ci = ((ks & 3) * 4 + lq) ^ ((tt - dd) & 7);
      const bf16x8 bb = *(const bf16x8*)(base + tt * 256 + ci * 16);
      acc1[0][n] = mfma16(a0, bb, acc1[0][n]);
      acc1[1][n] = mfma16(a1, bb, acc1[1][n]);
    }
  }

  {
    float ba[4], bs[4];
    #pragma unroll
    for (int r = 0; r < 4; ++r) {
      ba[r] = b_conv[layer * 256 + o0 + r];
      bs[r] = b_conv[layer * 256 + 128 + o0 + r];
    }
    #pragma unroll
    for (int n = 0; n < 4; ++n) {
      bf16x4 g4;
      #pragma unroll
      for (int r = 0; r < 4; ++r) {
        const float za = acc1[0][n][r] + ba[r];
        const float zb = acc1[1][n][r] + bs[r];
        const float th = 1.f - 2.f / (1.f + __expf(2.f * za));
        const float sg = 1.f / (1.f + __expf(-zb));
        g4[r] = f2b(th * sg);
      }
      const int tt = n * 16 + lh;
      *(bf16x4*)(ldsG + tt * GROWB + o0 * 2) = g4;
    }
  }
  __syncthreads();

  f32x4 acc2[4];
  #pragma unroll
  for (int n = 0; n < 4; ++n) acc2[n] = fz;
  const short* wol = wob + (size_t)layer * 16384;
  #pragma unroll
  for (int ks = 0; ks < 4; ++ks) {
    const bf16x8 a = *(const bf16x8*)(wol + (16 * w + lh) * 128 + ks * 32 + lq * 8);
    #pragma unroll
    for (int n = 0; n < 4; ++n) {
      const int tt = n * 16 + lh;
      const bf16x8 bb = *(const bf16x8*)(ldsG + tt * GROWB + ks * 64 + lq * 16);
      acc2[n] = mfma16(a, bb, acc2[n]);
    }
  }
  __syncthreads();

  f32x4 xn4[4];
  {
    float bo[4];
    #pragma unroll
    for (int r = 0; r < 4; ++r) bo[r] = b_out[layer * 128 + o0 + r];
    #pragma unroll
    for (int n = 0; n < 4; ++n) {
      const int tt = n * 16 + lh;
      const int ci = (o0 >> 3) ^ (tt & 7);
      const bf16x4 h4 = *(const bf16x4*)(ldsXC + tt * 256 + ci * 16 + (o0 & 7) * 2);
      f32x4 s4, xn;
      #pragma unroll
      for (int r = 0; r < 4; ++r) {
        s4[r] = acc2[n][r] + bo[r];
        xn[r] = s4[r] + b2f(h4[r]);
      }
      #pragma unroll
      for (int r = 0; r < 4; ++r) {
        const int o  = o0 + r;
        const int lg = tt >> 2;
        const int pg = (lg & 8) | ((lg ^ (o & 7)) & 7);
        *(float*)(ldsS + o * 256 + pg * 16 + (tt & 3) * 4) = s4[r];
      }
      if (!last) {
        bf16x4 x4;
        #pragma unroll
        for (int r = 0; r < 4; ++r) x4[r] = f2b(xn[r]);
        *(bf16x4*)(ldsXC + tt * 256 + ci * 16 + (o0 & 7) * 2) = x4;
      } else {
        xn4[n] = xn;
      }
    }
  }
  __syncthreads();

  const size_t XOFFS = (size_t)NB * NC * NT;
  {
    float* skipBase = out + XOFFS + ((size_t)((layer * NB + b) * NC)) * NT + t0;
    const int j8 = tid & 7;
    #pragma unroll
    for (int half = 0; half < 2; ++half) {
      const int o = half * 64 + (tid >> 3);
      #pragma unroll
      for (int k = 0; k < 2; ++k) {
        const int pg = (k * 8) | ((j8 ^ (o & 7)) & 7);
        const f32x4 v = *(const f32x4*)(ldsS + o * 256 + pg * 16);
        __builtin_nontemporal_store(v, (f32x4*)(skipBase + (size_t)o * NT + j8 * 4 + k * 32));
      }
    }
  }
  if (!last) {
    char* dstBase = (char*)xbout + ((size_t)(b * NT + t0)) * 256;
    #pragma unroll
    for (int k = 0; k < 2; ++k) {
      const int idx = k * 512 + tid;
      const int r = idx >> 4, p = idx & 15;
      *(f32x4*)(dstBase + r * 256 + p * 16) = *(const f32x4*)(ldsXC + r * 256 + p * 16);
    }
  } else {
    {
      #pragma unroll
      for (int n = 0; n < 4; ++n) {
        const int tt = n * 16 + lh;
        #pragma unroll
        for (int r = 0; r < 4; ++r)
          *(short*)(ldsXC + (o0 + r) * 128 + tt * 2) = f2b(xn4[n][r]);
      }
    }
    __syncthreads();
    float* xBase = out + ((size_t)(b * NC)) * NT + t0;
    const int j16 = tid & 15;
    #pragma unroll
    for (int k = 0; k < 4; ++k) {
      const int o = k * 32 + (tid >> 4);
      const bf16x4 v = *(const bf16x4*)(ldsXC + o * 128 + j16 * 8);
      f32x4 f;
      #pragma unroll
      for (int r = 0; r < 4; ++r) f[r] = b2f(v[r]);
      __builtin_nontemporal_store(f, (f32x4*)(xBase + (size_t)o * NT + j16 * 4));
    }
  }
}

extern "C" void kernel_launch(void* const* d_in, const int* in_sizes, int n_in,
                              void* d_out, int out_size, void* d_ws, size_t ws_size,
                              hipStream_t stream) {
  const float* x      = (const float*)d_in[0];
  const float* w_conv = (const float*)d_in[1];
  const float* b_conv = (const float*)d_in[2];
  const float* w_out  = (const float*)d_in[3];
  const float* b_out  = (const float*)d_in[4];
  float* out = (float*)d_out;

  const size_t XTN = (size_t)NB * NT * NC;
  short* xb[2];
  xb[0] = (short*)d_ws;
  xb[1] = xb[0] + XTN;
  short* wcb = xb[1] + XTN;
  short* wob = wcb + CONVN;

  prep<<<dim3(PACKB + TRANB), 256, 0, stream>>>(x, w_conv, w_out, xb[0], wcb, wob);

  int cur = 0;
  wavenet_pair<<<dim3(512), 512, 0, stream>>>(wcb, b_conv, wob, b_out,
                                              xb[cur], xb[cur ^ 1], out, 0, 1, 2);
  cur ^= 1;
  wavenet_pair<<<dim3(512), 512, 0, stream>>>(wcb, b_conv, wob, b_out,
                                              xb[cur], xb[cur ^ 1], out, 2, 4, 8);
  cur ^= 1;
  wavenet_pair6<<<dim3(512), 512, 0, stream>>>(wcb, b_conv, wob, b_out,
                                               xb[cur], xb[cur ^ 1], out, 4, 16, 32);
  cur ^= 1;
  for (int i = 6; i <= 9; ++i) {
    wavenet_layer<<<dim3(512), 512, 0, stream>>>(
        wcb, b_conv, wob, b_out, xb[cur], xb[cur ^ 1], out, i, 1 << i, 0);
    cur ^= 1;
  }
  wavenet_pair<<<dim3(512), 512, 0, stream>>>(wcb, b_conv, wob, b_out,
                                              xb[cur], xb[cur ^ 1], out, 10, 1, 2);
  cur ^= 1;
  wavenet_pair<<<dim3(512), 512, 0, stream>>>(wcb, b_conv, wob, b_out,
                                              xb[cur], xb[cur ^ 1], out, 12, 4, 8);
  cur ^= 1;
  wavenet_pair6<<<dim3(512), 512, 0, stream>>>(wcb, b_conv, wob, b_out,
                                               xb[cur], xb[cur ^ 1], out, 14, 16, 32);
  cur ^= 1;
  for (int i = 16; i <= 19; ++i) {
    wavenet_layer<<<dim3(512), 512, 0, stream>>>(
        wcb, b_conv, wob, b_out, xb[cur], xb[cur ^ 1], out, i, 1 << (i - 10),
        (i == 19) ? 1 : 0);
    cur ^= 1;
  }
}

// Round 21
// 332.248 us; speedup vs baseline: 2.0193x; 1.0367x over previous
//
#include <hip/hip_runtime.h>
#include <hip/hip_bf16.h>
#include <stdint.h>

using f32x4  = __attribute__((ext_vector_type(4))) float;
using bf16x8 = __attribute__((ext_vector_type(8))) short;
using bf16x4 = __attribute__((ext_vector_type(4))) short;

#define NB   4
#define NC   128
#define NT   8192
#define TL   64
#define NLAYER 20
#define GROWB 272
#define CONVN (NLAYER * 256 * 256)
#define WOUTN (NLAYER * 128 * 128)
#define PACKB ((CONVN + WOUTN + 255) / 256)
#define TRANB ((NT / 64) * (NC / 64) * NB)

__device__ __forceinline__ short f2b(float f) {
  union { float f; unsigned u; } v; v.f = f;
  unsigned r = v.u + 0x7FFFu + ((v.u >> 16) & 1u);   // RNE
  return (short)(r >> 16);
}

__device__ __forceinline__ float b2f(short s) {
  union { unsigned u; float f; } v;
  v.u = ((unsigned)(unsigned short)s) << 16;
  return v.f;
}

__device__ __forceinline__ f32x4 mfma16(bf16x8 a, bf16x8 b, f32x4 c) {
  return __builtin_amdgcn_mfma_f32_16x16x32_bf16(a, b, c, 0, 0, 0);
}

__device__ __forceinline__ void gl_lds16(const void* g, void* l) {
  __builtin_amdgcn_global_load_lds(
      (const __attribute__((address_space(1))) void*)g,
      (__attribute__((address_space(3))) void*)l, 16, 0, 0);
}

// Fused prep: blocks [0, PACKB) pack weights; blocks [PACKB, PACKB+TRANB)
// transpose x -> xtb (bf16 swizzled 256B rows, 16B groups XOR t&7).
__global__ void prep(const float* __restrict__ x,
                     const float* __restrict__ w_conv,
                     const float* __restrict__ w_out,
                     short* __restrict__ xtb,
                     short* __restrict__ wcb, short* __restrict__ wob) {
  __shared__ float tile[64][65];
  if (blockIdx.x < PACKB) {
    const int idx = blockIdx.x * 256 + threadIdx.x;
    if (idx < CONVN) {
      const int k = idx & 255, o = (idx >> 8) & 255, lyr = idx >> 16;
      const int tap = k >> 7, c = k & 127;
      wcb[idx] = f2b(w_conv[(((size_t)lyr * 256 + o) * 128 + c) * 2 + tap]);
    } else if (idx < CONVN + WOUTN) {
      const int j = idx - CONVN;
      wob[j] = f2b(w_out[j]);
    }
    return;
  }
  const int bid2 = blockIdx.x - PACKB;
  const int t0 = (bid2 & 127) * 64;
  const int c0 = ((bid2 >> 7) & 1) * 64;
  const int b  = bid2 >> 8;
  const int lane = threadIdx.x & 63;
  const int r4   = threadIdx.x >> 6;
  #pragma unroll
  for (int i = 0; i < 16; ++i) {
    const int cl = i * 4 + r4;
    tile[cl][lane] = x[((size_t)(b * NC + c0 + cl)) * NT + t0 + lane];
  }
  __syncthreads();
  #pragma unroll
  for (int it = 0; it < 2; ++it) {
    const int idx = it * 256 + threadIdx.x;
    const int r  = idx >> 3;
    const int gi = idx & 7;
    bf16x8 v;
    #pragma unroll
    for (int jj = 0; jj < 8; ++jj) v[jj] = f2b(tile[gi * 8 + jj][r]);
    const int t = t0 + r;
    const int ci = ((c0 >> 3) + gi) ^ (t & 7);
    *(bf16x8*)((char*)xtb + ((size_t)(b * NT + t)) * 256 + ci * 16) = v;
  }
}

// ---- fused quad (L0..L0+3), d = 1,2,4,8. X: 96 rows [t0-32, t0+64). ----
// Y buffers 80 rows [t0-16, t0+64). G: layer0 -> Yq, layers 1..3 -> dead X.
__global__ __launch_bounds__(512, 4)
void wavenet_quad(const short* __restrict__ wcb,
                  const float* __restrict__ b_conv,
                  const short* __restrict__ wob,
                  const float* __restrict__ b_out,
                  const short* __restrict__ xbin,
                  short* __restrict__ xbout,
                  float* __restrict__ out,
                  int L0)
{
  __shared__ char ldsX [96 * 256];   // 24576
  __shared__ char ldsYp[80 * 256];   // 20480
  __shared__ char ldsYq[80 * 256];   // 20480

  const int tid = threadIdx.x;
  const int w = tid >> 6, l = tid & 63, lh = l & 15, lq = l >> 4;
  const int o0 = 16 * w + lq * 4;
  const int uid = (blockIdx.x & 7) * 64 + (blockIdx.x >> 3);
  const int b   = uid >> 7;
  const int t0  = (uid & 127) * 64;
  const bool zhalo = (t0 == 0);
  const f32x4 fz = {0.f, 0.f, 0.f, 0.f};
  const size_t XOFFS = (size_t)NB * NC * NT;

  // ---- stage X: 96 rows [t0-32, t0+64) ----
  if (!zhalo) {
    const char* src = (const char*)xbin + ((size_t)(b * NT + t0 - 32)) * 256;
    #pragma unroll
    for (int k = 0; k < 3; ++k)
      gl_lds16(src + k * 8192 + tid * 16, ldsX + k * 8192 + tid * 16);
  } else {
    bf16x8 z = {0, 0, 0, 0, 0, 0, 0, 0};
    *(bf16x8*)(ldsX + tid * 16) = z;                  // rows [0,32) = 8192 B
    const char* src = (const char*)xbin + ((size_t)(b * NT)) * 256;
    gl_lds16(src + tid * 16,        ldsX + 8192 + tid * 16);
    gl_lds16(src + tid * 16 + 8192, ldsX + 8192 + tid * 16 + 8192);
  }
  __syncthreads();

  #pragma unroll
  for (int j = 0; j < 4; ++j) {
    const int Lj = L0 + j;
    const int d  = 1 << j;
    const char* SRC = (j == 0) ? ldsX : ((j == 2) ? ldsYq : ldsYp);
    char*       DST = (j == 1 || j == 3) ? ldsYq : ldsYp;
    char*       G   = (j == 0) ? ldsYq : ldsX;
    const int roff  = (j == 0) ? 16 : 0;    // SRC row = Y row + roff
    const int qb    = (j == 3) ? 16 : 0;    // layer 3: owned tiles only
    const int ntl   = (j == 3) ? 4  : 5;

    // ---- GEMM1 + gate -> G ----
    f32x4 acc1[2][5];
    #pragma unroll
    for (int mi = 0; mi < 2; ++mi)
      #pragma unroll
      for (int nn = 0; nn < 5; ++nn) acc1[mi][nn] = fz;
    {
      const short* wl = wcb + (size_t)Lj * 65536;
      #pragma unroll
      for (int ks = 0; ks < 8; ++ks) {
        const bf16x8 a0 = *(const bf16x8*)(wl + (16 * w + lh) * 256 + ks * 32 + lq * 8);
        const bf16x8 a1 = *(const bf16x8*)(wl + (128 + 16 * w + lh) * 256 + ks * 32 + lq * 8);
        const int dd = (ks < 4) ? d : 0;
        #pragma unroll
        for (int nn = 0; nn < 5; ++nn) if (nn < ntl) {
          int sr = qb + nn * 16 + lh + roff - dd;
          if (sr < 0) sr += 80;               // wrapped rows never consumed
          const int ci = ((ks & 3) * 4 + lq) ^ (sr & 7);
          const bf16x8 bb = *(const bf16x8*)(SRC + sr * 256 + ci * 16);
          acc1[0][nn] = mfma16(a0, bb, acc1[0][nn]);
          acc1[1][nn] = mfma16(a1, bb, acc1[1][nn]);
        }
      }
    }
    {
      float ba[4], bs[4];
      #pragma unroll
      for (int r = 0; r < 4; ++r) {
        ba[r] = b_conv[Lj * 256 + o0 + r];
        bs[r] = b_conv[Lj * 256 + 128 + o0 + r];
      }
      #pragma unroll
      for (int nn = 0; nn < 5; ++nn) if (nn < ntl) {
        bf16x4 g4;
        #pragma unroll
        for (int r = 0; r < 4; ++r) {
          const float za = acc1[0][nn][r] + ba[r];
          const float zb = acc1[1][nn][r] + bs[r];
          const float th = 1.f - 2.f / (1.f + __expf(2.f * za));
          const float sg = 1.f / (1.f + __expf(-zb));
          g4[r] = f2b(th * sg);
        }
        const int q = qb + nn * 16 + lh;
        const int ci = (o0 >> 3) ^ (q & 7);
        *(bf16x4*)(G + q * 256 + ci * 16 + (o0 & 7) * 2) = g4;
      }
    }
    __syncthreads();

    // ---- GEMM2 + epilogue ----
    {
      f32x4 acc2[5];
      #pragma unroll
      for (int nn = 0; nn < 5; ++nn) acc2[nn] = fz;
      const short* wol = wob + (size_t)Lj * 16384;
      #pragma unroll
      for (int ks = 0; ks < 4; ++ks) {
        const bf16x8 a = *(const bf16x8*)(wol + (16 * w + lh) * 128 + ks * 32 + lq * 8);
        #pragma unroll
        for (int nn = 0; nn < 5; ++nn) if (nn < ntl) {
          const int q = qb + nn * 16 + lh;
          const int ci = (ks * 4 + lq) ^ (q & 7);
          const bf16x8 bb = *(const bf16x8*)(G + q * 256 + ci * 16);
          acc2[nn] = mfma16(a, bb, acc2[nn]);
        }
      }
      float bo[4];
      #pragma unroll
      for (int r = 0; r < 4; ++r) bo[r] = b_out[Lj * 128 + o0 + r];
      float* skipBase = out + XOFFS + ((size_t)((Lj * NB + b) * NC)) * NT + t0;
      #pragma unroll
      for (int nn = 0; nn < 5; ++nn) if (nn < ntl) {
        const int q  = qb + nn * 16 + lh;     // Y row; t = t0 - 16 + q
        const int hr = q + roff;              // residual source row
        const int cih = (o0 >> 3) ^ (hr & 7);
        const bf16x4 h4 = *(const bf16x4*)(SRC + hr * 256 + cih * 16 + (o0 & 7) * 2);
        f32x4 s4, xn;
        #pragma unroll
        for (int r = 0; r < 4; ++r) {
          s4[r] = acc2[nn][r] + bo[r];
          xn[r] = s4[r] + b2f(h4[r]);
        }
        if (q >= 16) {                        // owned rows: NT skip stores
          const int tt = q - 16;
          #pragma unroll
          for (int r = 0; r < 4; ++r)
            __builtin_nontemporal_store(s4[r], skipBase + (size_t)(o0 + r) * NT + tt);
        }
        bf16x4 x4;
        #pragma unroll
        for (int r = 0; r < 4; ++r) x4[r] = f2b(xn[r]);
        if (zhalo && q < 16) { x4[0] = 0; x4[1] = 0; x4[2] = 0; x4[3] = 0; }
        const int ciq = (o0 >> 3) ^ (q & 7);
        *(bf16x4*)(DST + q * 256 + ciq * 16 + (o0 & 7) * 2) = x4;
      }
    }
    __syncthreads();
  }

  // ---- x_{L0+4} -> xbout: verbatim rows [16,80) of Yq ----
  {
    char* dstBase = (char*)xbout + ((size_t)(b * NT + t0)) * 256;
    #pragma unroll
    for (int k = 0; k < 2; ++k) {
      const int idx = k * 512 + tid;
      const int r = idx >> 4, pcol = idx & 15;
      *(f32x4*)(dstBase + r * 256 + pcol * 16) =
          *(const f32x4*)(ldsYq + (16 + r) * 256 + pcol * 16);
    }
  }
}

// ---- fused pair variant B (L, L+1), d1 <= 16, d2 <= 32. X: 112 rows. ----
__global__ __launch_bounds__(512, 4)
void wavenet_pair6(const short* __restrict__ wcb,
                   const float* __restrict__ b_conv,
                   const short* __restrict__ wob,
                   const float* __restrict__ b_out,
                   const short* __restrict__ xbin,
                   short* __restrict__ xbout,
                   float* __restrict__ out,
                   int L, int d1, int d2)
{
  __shared__ char ldsY[96 * 256];
  __shared__ char ldsXG[112 * 256 + 96 * 256];   // X 28672 + G 24576
  char* X = ldsXG;
  char* G = ldsXG + 112 * 256;
  char* S = ldsXG;

  const int tid = threadIdx.x;
  const int w = tid >> 6, l = tid & 63, lh = l & 15, lq = l >> 4;
  const int o0 = 16 * w + lq * 4;
  const int uid = (blockIdx.x & 7) * 64 + (blockIdx.x >> 3);
  const int b   = uid >> 7;
  const int t0  = (uid & 127) * 64;
  const bool zhalo = (t0 == 0);
  const f32x4 fz = {0.f, 0.f, 0.f, 0.f};
  const size_t XOFFS = (size_t)NB * NC * NT;

  if (!zhalo) {
    const char* src = (const char*)xbin + ((size_t)(b * NT + t0 - 48)) * 256;
    #pragma unroll
    for (int k = 0; k < 4; ++k) {
      const int off = k * 8192 + tid * 16;
      if (off < 112 * 256) gl_lds16(src + off, X + off);
    }
  } else {
    if (tid * 16 < 12288) {
      bf16x8 z = {0, 0, 0, 0, 0, 0, 0, 0};
      *(bf16x8*)(X + tid * 16) = z;
      if (tid * 16 + 8192 < 12288) *(bf16x8*)(X + tid * 16 + 8192) = z;
    }
    const char* src = (const char*)xbin + ((size_t)(b * NT)) * 256;
    gl_lds16(src + tid * 16,        X + 12288 + tid * 16);
    gl_lds16(src + tid * 16 + 8192, X + 12288 + tid * 16 + 8192);
  }
  __syncthreads();                                           // B1

  f32x4 acc1[2][6];
  #pragma unroll
  for (int mi = 0; mi < 2; ++mi)
    #pragma unroll
    for (int nn = 0; nn < 6; ++nn) acc1[mi][nn] = fz;
  {
    const short* wl = wcb + (size_t)L * 65536;
    #pragma unroll
    for (int ks = 0; ks < 8; ++ks) {
      const bf16x8 a0 = *(const bf16x8*)(wl + (16 * w + lh) * 256 + ks * 32 + lq * 8);
      const bf16x8 a1 = *(const bf16x8*)(wl + (128 + 16 * w + lh) * 256 + ks * 32 + lq * 8);
      const int dd = (ks < 4) ? d1 : 0;
      #pragma unroll
      for (int nn = 0; nn < 6; ++nn) {
        const int p = 16 + nn * 16 + lh - dd;
        const int ci = ((ks & 3) * 4 + lq) ^ (p & 7);
        const bf16x8 bb = *(const bf16x8*)(X + p * 256 + ci * 16);
        acc1[0][nn] = mfma16(a0, bb, acc1[0][nn]);
        acc1[1][nn] = mfma16(a1, bb, acc1[1][nn]);
      }
    }
  }
  {
    float ba[4], bs[4];
    #pragma unroll
    for (int r = 0; r < 4; ++r) {
      ba[r] = b_conv[L * 256 + o0 + r];
      bs[r] = b_conv[L * 256 + 128 + o0 + r];
    }
    #pragma unroll
    for (int nn = 0; nn < 6; ++nn) {
      bf16x4 g4;
      #pragma unroll
      for (int r = 0; r < 4; ++r) {
        const float za = acc1[0][nn][r] + ba[r];
        const float zb = acc1[1][nn][r] + bs[r];
        const float th = 1.f - 2.f / (1.f + __expf(2.f * za));
        const float sg = 1.f / (1.f + __expf(-zb));
        g4[r] = f2b(th * sg);
      }
      const int q = nn * 16 + lh;
      const int ci = (o0 >> 3) ^ (q & 7);
      *(bf16x4*)(G + q * 256 + ci * 16 + (o0 & 7) * 2) = g4;
    }
  }
  __syncthreads();                                           // B2

  f32x4 s4vL[4];
  {
    f32x4 acc2[6];
    #pragma unroll
    for (int nn = 0; nn < 6; ++nn) acc2[nn] = fz;
    const short* wol = wob + (size_t)L * 16384;
    #pragma unroll
    for (int ks = 0; ks < 4; ++ks) {
      const bf16x8 a = *(const bf16x8*)(wol + (16 * w + lh) * 128 + ks * 32 + lq * 8);
      #pragma unroll
      for (int nn = 0; nn < 6; ++nn) {
        const int q = nn * 16 + lh;
        const int ci = (ks * 4 + lq) ^ (q & 7);
        const bf16x8 bb = *(const bf16x8*)(G + q * 256 + ci * 16);
        acc2[nn] = mfma16(a, bb, acc2[nn]);
      }
    }
    float bo[4];
    #pragma unroll
    for (int r = 0; r < 4; ++r) bo[r] = b_out[L * 128 + o0 + r];
    #pragma unroll
    for (int nn = 0; nn < 6; ++nn) {
      const int q = nn * 16 + lh;
      const int p = q + 16;
      const int ci = (o0 >> 3) ^ (q & 7);
      const bf16x4 h4 = *(const bf16x4*)(X + p * 256 + ci * 16 + (o0 & 7) * 2);
      f32x4 s4, xn;
      #pragma unroll
      for (int r = 0; r < 4; ++r) {
        s4[r] = acc2[nn][r] + bo[r];
        xn[r] = s4[r] + b2f(h4[r]);
      }
      if (nn >= 2) s4vL[nn - 2] = s4;
      bf16x4 x4;
      #pragma unroll
      for (int r = 0; r < 4; ++r) x4[r] = f2b(xn[r]);
      if (zhalo && nn < 2) { x4[0] = 0; x4[1] = 0; x4[2] = 0; x4[3] = 0; }
      *(bf16x4*)(ldsY + q * 256 + ci * 16 + (o0 & 7) * 2) = x4;
    }
  }
  __syncthreads();                                           // B3

  #pragma unroll
  for (int nn = 0; nn < 4; ++nn) {
    const int tt = nn * 16 + lh;
    #pragma unroll
    for (int r = 0; r < 4; ++r) {
      const int o  = o0 + r;
      const int lg = tt >> 2;
      const int pg = (lg & 8) | ((lg ^ (o & 7)) & 7);
      *(float*)(S + o * 256 + pg * 16 + (tt & 3) * 4) = s4vL[nn][r];
    }
  }
  __syncthreads();                                           // B4

  f32x4 acc1b[2][4];
  #pragma unroll
  for (int mi = 0; mi < 2; ++mi)
    #pragma unroll
    for (int n = 0; n < 4; ++n) acc1b[mi][n] = fz;
  {
    float* skipBase = out + XOFFS + ((size_t)((L * NB + b) * NC)) * NT + t0;
    const int j8 = tid & 7;
    #pragma unroll
    for (int half = 0; half < 2; ++half) {
      const int o = half * 64 + (tid >> 3);
      #pragma unroll
      for (int k = 0; k < 2; ++k) {
        const int pg = (k * 8) | ((j8 ^ (o & 7)) & 7);
        const f32x4 v = *(const f32x4*)(S + o * 256 + pg * 16);
        __builtin_nontemporal_store(v, (f32x4*)(skipBase + (size_t)o * NT + j8 * 4 + k * 32));
      }
    }
    const short* wl2 = wcb + (size_t)(L + 1) * 65536;
    #pragma unroll
    for (int ks = 0; ks < 8; ++ks) {
      const bf16x8 a0 = *(const bf16x8*)(wl2 + (16 * w + lh) * 256 + ks * 32 + lq * 8);
      const bf16x8 a1 = *(const bf16x8*)(wl2 + (128 + 16 * w + lh) * 256 + ks * 32 + lq * 8);
      const int dd = (ks < 4) ? d2 : 0;
      #pragma unroll
      for (int n = 0; n < 4; ++n) {
        const int qy = 32 + n * 16 + lh - dd;
        const int ci = ((ks & 3) * 4 + lq) ^ (qy & 7);
        const bf16x8 bb = *(const bf16x8*)(ldsY + qy * 256 + ci * 16);
        acc1b[0][n] = mfma16(a0, bb, acc1b[0][n]);
        acc1b[1][n] = mfma16(a1, bb, acc1b[1][n]);
      }
    }
  }
  __syncthreads();                                           // B5

  {
    float ba[4], bs[4];
    #pragma unroll
    for (int r = 0; r < 4; ++r) {
      ba[r] = b_conv[(L + 1) * 256 + o0 + r];
      bs[r] = b_conv[(L + 1) * 256 + 128 + o0 + r];
    }
    #pragma unroll
    for (int n = 0; n < 4; ++n) {
      bf16x4 g4;
      #pragma unroll
      for (int r = 0; r < 4; ++r) {
        const float za = acc1b[0][n][r] + ba[r];
        const float zb = acc1b[1][n][r] + bs[r];
        const float th = 1.f - 2.f / (1.f + __expf(2.f * za));
        const float sg = 1.f / (1.f + __expf(-zb));
        g4[r] = f2b(th * sg);
      }
      const int q2 = n * 16 + lh;
      const int ci = (o0 >> 3) ^ (q2 & 7);
      *(bf16x4*)(G + q2 * 256 + ci * 16 + (o0 & 7) * 2) = g4;
    }
  }
  __syncthreads();                                           // B6

  f32x4 s4vP[4];
  {
    f32x4 acc2[4];
    #pragma unroll
    for (int n = 0; n < 4; ++n) acc2[n] = fz;
    const short* wol2 = wob + (size_t)(L + 1) * 16384;
    #pragma unroll
    for (int ks = 0; ks < 4; ++ks) {
      const bf16x8 a = *(const bf16x8*)(wol2 + (16 * w + lh) * 128 + ks * 32 + lq * 8);
      #pragma unroll
      for (int n = 0; n < 4; ++n) {
        const int q2 = n * 16 + lh;
        const int ci = (ks * 4 + lq) ^ (q2 & 7);
        const bf16x8 bb = *(const bf16x8*)(G + q2 * 256 + ci * 16);
        acc2[n] = mfma16(a, bb, acc2[n]);
      }
    }
    float bo[4];
    #pragma unroll
    for (int r = 0; r < 4; ++r) bo[r] = b_out[(L + 1) * 128 + o0 + r];
    #pragma unroll
    for (int n = 0; n < 4; ++n) {
      const int q = 32 + n * 16 + lh;
      const int ci = (o0 >> 3) ^ (q & 7);
      const bf16x4 h4 = *(const bf16x4*)(ldsY + q * 256 + ci * 16 + (o0 & 7) * 2);
      f32x4 s4, xn;
      #pragma unroll
      for (int r = 0; r < 4; ++r) {
        s4[r] = acc2[n][r] + bo[r];
        xn[r] = s4[r] + b2f(h4[r]);
      }
      s4vP[n] = s4;
      bf16x4 x4;
      #pragma unroll
      for (int r = 0; r < 4; ++r) x4[r] = f2b(xn[r]);
      *(bf16x4*)(ldsY + q * 256 + ci * 16 + (o0 & 7) * 2) = x4;
    }
  }
  __syncthreads();                                           // B7

  #pragma unroll
  for (int n = 0; n < 4; ++n) {
    const int tt = n * 16 + lh;
    #pragma unroll
    for (int r = 0; r < 4; ++r) {
      const int o  = o0 + r;
      const int lg = tt >> 2;
      const int pg = (lg & 8) | ((lg ^ (o & 7)) & 7);
      *(float*)(S + o * 256 + pg * 16 + (tt & 3) * 4) = s4vP[n][r];
    }
  }
  __syncthreads();                                           // B8

  {
    float* skipBase = out + XOFFS + ((size_t)(((L + 1) * NB + b) * NC)) * NT + t0;
    const int j8 = tid & 7;
    #pragma unroll
    for (int half = 0; half < 2; ++half) {
      const int o = half * 64 + (tid >> 3);
      #pragma unroll
      for (int k = 0; k < 2; ++k) {
        const int pg = (k * 8) | ((j8 ^ (o & 7)) & 7);
        const f32x4 v = *(const f32x4*)(S + o * 256 + pg * 16);
        __builtin_nontemporal_store(v, (f32x4*)(skipBase + (size_t)o * NT + j8 * 4 + k * 32));
      }
    }
    char* dstBase = (char*)xbout + ((size_t)(b * NT + t0)) * 256;
    #pragma unroll
    for (int k = 0; k < 2; ++k) {
      const int idx = k * 512 + tid;
      const int r = idx >> 4, pcol = idx & 15;
      *(f32x4*)(dstBase + r * 256 + pcol * 16) =
          *(const f32x4*)(ldsY + (32 + r) * 256 + pcol * 16);
    }
  }
}

// ---- single layer (R8 structure: S-bounce + NT full-line stores) ----
__global__ __launch_bounds__(512, 4)
void wavenet_layer(const short* __restrict__ wcb,
                   const float* __restrict__ b_conv,
                   const short* __restrict__ wob,
                   const float* __restrict__ b_out,
                   const short* __restrict__ xbin,
                   short* __restrict__ xbout,
                   float* __restrict__ out,
                   int layer, int dil, int last)
{
  __shared__ char ldsXC[TL * 256];
  __shared__ char ldsSP[TL * 256 + TL * GROWB];
  char* ldsXP = ldsSP;
  char* ldsG  = ldsSP + TL * 256;
  char* ldsS  = ldsSP;

  const int tid = threadIdx.x;
  const int w   = tid >> 6;
  const int l   = tid & 63;
  const int lh  = l & 15;
  const int lq  = l >> 4;
  const int o0  = 16 * w + lq * 4;
  const int uid = (blockIdx.x & 7) * 64 + (blockIdx.x >> 3);
  const int b   = uid >> 7;
  const int t0  = (uid & 127) * 64;

  {
    const char* xcg = (const char*)xbin + ((size_t)(b * NT + t0)) * 256;
    const int off = w * 2048 + l * 16;
    gl_lds16(xcg + off, ldsXC + off);
    gl_lds16(xcg + off + 1024, ldsXC + off + 1024);
  }
  if (t0 >= dil) {
    const char* xpg = (const char*)xbin + ((size_t)(b * NT + t0 - dil)) * 256;
    const int off = w * 2048 + l * 16;
    gl_lds16(xpg + off, ldsXP + off);
    gl_lds16(xpg + off + 1024, ldsXP + off + 1024);
  } else {
    const int row = tid >> 3, j8 = tid & 7;
    const int tp = t0 + row - dil;
    char* dst = ldsXP + row * 256;
    if (tp >= 0) {
      const char* src = (const char*)xbin + ((size_t)(b * NT + tp)) * 256;
      *(bf16x8*)(dst + j8 * 16)       = *(const bf16x8*)(src + j8 * 16);
      *(bf16x8*)(dst + j8 * 16 + 128) = *(const bf16x8*)(src + j8 * 16 + 128);
    } else {
      bf16x8 z = {0, 0, 0, 0, 0, 0, 0, 0};
      *(bf16x8*)(dst + j8 * 16)       = z;
      *(bf16x8*)(dst + j8 * 16 + 128) = z;
    }
  }
  __syncthreads();

  const f32x4 fz = {0.f, 0.f, 0.f, 0.f};
  f32x4 acc1[2][4];
  #pragma unroll
  for (int mi = 0; mi < 2; ++mi)
    #pragma unroll
    for (int n = 0; n < 4; ++n) acc1[mi][n] = fz;

  const short* wl = wcb + (size_t)layer * 65536;
  #pragma unroll
  for (int ks = 0; ks < 8; ++ks) {
    const bf16x8 a0 = *(const bf16x8*)(wl + (16 * w + lh) * 256 + ks * 32 + lq * 8);
    const bf16x8 a1 = *(const bf16x8*)(wl + (128 + 16 * w + lh) * 256 + ks * 32 + lq * 8);
    const char* base = (ks < 4) ? ldsXP : ldsXC;
    const int dd = (ks < 4) ? dil : 0;
    #pragma unroll
    for (int n = 0; n < 4; ++n) {
      const int tt = n * 16 + lh;
      const int ci = ((ks & 3) * 4 + lq) ^ ((tt - dd) & 7);
      const bf16x8 bb = *(const bf16x8*)(base + tt * 256 + ci * 16);
      acc1[0][n] = mfma16(a0, bb, acc1[0][n]);
      acc1[1][n] = mfma16(a1, bb, acc1[1][n]);
    }
  }

  {
    float ba[4], bs[4];
    #pragma unroll
    for (int r = 0; r < 4; ++r) {
      ba[r] = b_conv[layer * 256 + o0 + r];
      bs[r] = b_conv[layer * 256 + 128 + o0 + r];
    }
    #pragma unroll
    for (int n = 0; n < 4; ++n) {
      bf16x4 g4;
      #pragma unroll
      for (int r = 0; r < 4; ++r) {
        const float za = acc1[0][n][r] + ba[r];
        const float zb = acc1[1][n][r] + bs[r];
        const float th = 1.f - 2.f / (1.f + __expf(2.f * za));
        const float sg = 1.f / (1.f + __expf(-zb));
        g4[r] = f2b(th * sg);
      }
      const int tt = n * 16 + lh;
      *(bf16x4*)(ldsG + tt * GROWB + o0 * 2) = g4;
    }
  }
  __syncthreads();

  f32x4 acc2[4];
  #pragma unroll
  for (int n = 0; n < 4; ++n) acc2[n] = fz;
  const short* wol = wob + (size_t)layer * 16384;
  #pragma unroll
  for (int ks = 0; ks < 4; ++ks) {
    const bf16x8 a = *(const bf16x8*)(wol + (16 * w + lh) * 128 + ks * 32 + lq * 8);
    #pragma unroll
    for (int n = 0; n < 4; ++n) {
      const int tt = n * 16 + lh;
      const bf16x8 bb = *(const bf16x8*)(ldsG + tt * GROWB + ks * 64 + lq * 16);
      acc2[n] = mfma16(a, bb, acc2[n]);
    }
  }
  __syncthreads();

  f32x4 xn4[4];
  {
    float bo[4];
    #pragma unroll
    for (int r = 0; r < 4; ++r) bo[r] = b_out[layer * 128 + o0 + r];
    #pragma unroll
    for (int n = 0; n < 4; ++n) {
      const int tt = n * 16 + lh;
      const int ci = (o0 >> 3) ^ (tt & 7);
      const bf16x4 h4 = *(const bf16x4*)(ldsXC + tt * 256 + ci * 16 + (o0 & 7) * 2);
      f32x4 s4, xn;
      #pragma unroll
      for (int r = 0; r < 4; ++r) {
        s4[r] = acc2[n][r] + bo[r];
        xn[r] = s4[r] + b2f(h4[r]);
      }
      #pragma unroll
      for (int r = 0; r < 4; ++r) {
        const int o  = o0 + r;
        const int lg = tt >> 2;
        const int pg = (lg & 8) | ((lg ^ (o & 7)) & 7);
        *(float*)(ldsS + o * 256 + pg * 16 + (tt & 3) * 4) = s4[r];
      }
      if (!last) {
        bf16x4 x4;
        #pragma unroll
        for (int r = 0; r < 4; ++r) x4[r] = f2b(xn[r]);
        *(bf16x4*)(ldsXC + tt * 256 + ci * 16 + (o0 & 7) * 2) = x4;
      } else {
        xn4[n] = xn;
      }
    }
  }
  __syncthreads();

  const size_t XOFFS = (size_t)NB * NC * NT;
  {
    float* skipBase = out + XOFFS + ((size_t)((layer * NB + b) * NC)) * NT + t0;
    const int j8 = tid & 7;
    #pragma unroll
    for (int half = 0; half < 2; ++half) {
      const int o = half * 64 + (tid >> 3);
      #pragma unroll
      for (int k = 0; k < 2; ++k) {
        const int pg = (k * 8) | ((j8 ^ (o & 7)) & 7);
        const f32x4 v = *(const f32x4*)(ldsS + o * 256 + pg * 16);
        __builtin_nontemporal_store(v, (f32x4*)(skipBase + (size_t)o * NT + j8 * 4 + k * 32));
      }
    }
  }
  if (!last) {
    char* dstBase = (char*)xbout + ((size_t)(b * NT + t0)) * 256;
    #pragma unroll
    for (int k = 0; k < 2; ++k) {
      const int idx = k * 512 + tid;
      const int r = idx >> 4, p = idx & 15;
      *(f32x4*)(dstBase + r * 256 + p * 16) = *(const f32x4*)(ldsXC + r * 256 + p * 16);
    }
  } else {
    {
      #pragma unroll
      for (int n = 0; n < 4; ++n) {
        const int tt = n * 16 + lh;
        #pragma unroll
        for (int r = 0; r < 4; ++r)
          *(short*)(ldsXC + (o0 + r) * 128 + tt * 2) = f2b(xn4[n][r]);
      }
    }
    __syncthreads();
    float* xBase = out + ((size_t)(b * NC)) * NT + t0;
    const int j16 = tid & 15;
    #pragma unroll
    for (int k = 0; k < 4; ++k) {
      const int o = k * 32 + (tid >> 4);
      const bf16x4 v = *(const bf16x4*)(ldsXC + o * 128 + j16 * 8);
      f32x4 f;
      #pragma unroll
      for (int r = 0; r < 4; ++r) f[r] = b2f(v[r]);
      __builtin_nontemporal_store(f, (f32x4*)(xBase + (size_t)o * NT + j16 * 4));
    }
  }
}

extern "C" void kernel_launch(void* const* d_in, const int* in_sizes, int n_in,
                              void* d_out, int out_size, void* d_ws, size_t ws_size,
                              hipStream_t stream) {
  const float* x      = (const float*)d_in[0];
  const float* w_conv = (const float*)d_in[1];
  const float* b_conv = (const float*)d_in[2];
  const float* w_out  = (const float*)d_in[3];
  const float* b_out  = (const float*)d_in[4];
  float* out = (float*)d_out;

  const size_t XTN = (size_t)NB * NT * NC;
  short* xb[2];
  xb[0] = (short*)d_ws;
  xb[1] = xb[0] + XTN;
  short* wcb = xb[1] + XTN;
  short* wob = wcb + CONVN;

  prep<<<dim3(PACKB + TRANB), 256, 0, stream>>>(x, w_conv, w_out, xb[0], wcb, wob);

  int cur = 0;
  // layers 0-3 fused quad
  wavenet_quad<<<dim3(512), 512, 0, stream>>>(wcb, b_conv, wob, b_out,
                                              xb[cur], xb[cur ^ 1], out, 0);
  cur ^= 1;
  // layers 4-5
  wavenet_pair6<<<dim3(512), 512, 0, stream>>>(wcb, b_conv, wob, b_out,
                                               xb[cur], xb[cur ^ 1], out, 4, 16, 32);
  cur ^= 1;
  // singles 6..9 (d = 64..512)
  for (int i = 6; i <= 9; ++i) {
    wavenet_layer<<<dim3(512), 512, 0, stream>>>(
        wcb, b_conv, wob, b_out, xb[cur], xb[cur ^ 1], out, i, 1 << i, 0);
    cur ^= 1;
  }
  // layers 10-13 fused quad
  wavenet_quad<<<dim3(512), 512, 0, stream>>>(wcb, b_conv, wob, b_out,
                                              xb[cur], xb[cur ^ 1], out, 10);
  cur ^= 1;
  // layers 14-15
  wavenet_pair6<<<dim3(512), 512, 0, stream>>>(wcb, b_conv, wob, b_out,
                                               xb[cur], xb[cur ^ 1], out, 14, 16, 32);
  cur ^= 1;
  // singles 16..19 (d = 64..512)
  for (int i = 16; i <= 19; ++i) {
    wavenet_layer<<<dim3(512), 512, 0, stream>>>(
        wcb, b_conv, wob, b_out, xb[cur], xb[cur ^ 1], out, i, 1 << (i - 10),
        (i == 19) ? 1 : 0);
    cur ^= 1;
  }
}